// Round 9
// baseline (567.703 us; speedup 1.0000x reference)
//
#include <hip/hip_runtime.h>
#include <cstdint>
#include <cstddef>

#define NUM_USERS 100000
#define NUM_ITEMS 50000
#define NUM_NODES 150000
#define NUM_EDGES 2000000
#define BATCH 16384
#define BSHIFT 8                                   // 256 nodes per bucket
#define NBUCK ((NUM_NODES + 255) >> BSHIFT)        // 586 buckets
#define PA_EDGES 8192                              // edges per block, bhist/bpart
#define PA_BLOCKS ((NUM_EDGES + PA_EDGES - 1) / PA_EDGES)  // 245
#define NNPAD 150016                               // NUM_NODES rounded to 128
#define TBLK3 (NNPAD / 64)                         // 2344 blocks (4 waves x 16 nodes)

typedef _Float16 hf8 __attribute__((ext_vector_type(8)));
typedef _Float16 hf4 __attribute__((ext_vector_type(4)));
typedef float fx4 __attribute__((ext_vector_type(4)));

// ---------------- setup: nodelist + counters zero + aggX pad-row zero ----------------
__global__ void flag_kernel(const int* __restrict__ uid, const int* __restrict__ iid,
                            int* __restrict__ nodelist, int* __restrict__ bcnt,
                            int* __restrict__ gcnt,
                            _Float16* __restrict__ aXhi, _Float16* __restrict__ aXlo) {
  int i = blockIdx.x * blockDim.x + threadIdx.x;
  if (i < NBUCK) bcnt[i] = 0;
  if (i < 2) gcnt[i] = 0;
  // zero the 16 pad rows (NNPAD - NUM_NODES) of both f16 planes: 2048 floats each.
  if (i < 2048) {
    ((float*)(aXhi + (size_t)NUM_NODES * 256))[i] = 0.f;
    ((float*)(aXlo + (size_t)NUM_NODES * 256))[i] = 0.f;
  }
  if (i < BATCH) {
    nodelist[2 * i] = uid[i];
    nodelist[2 * i + 1] = NUM_USERS + iid[i];
  }
}

// ---------------- bucketed CSR construction ----------------
__global__ __launch_bounds__(256) void bhist_kernel(const int* __restrict__ dst,
                                                    int* __restrict__ bcnt) {
  __shared__ int bh[NBUCK];
  int t = threadIdx.x;
  for (int u = t; u < NBUCK; u += 256) bh[u] = 0;
  __syncthreads();
  int base = blockIdx.x * PA_EDGES;
#pragma unroll
  for (int u = 0; u < PA_EDGES / 256; ++u) {
    int e = base + u * 256 + t;
    if (e < NUM_EDGES) atomicAdd(&bh[dst[e] >> BSHIFT], 1);
  }
  __syncthreads();
  for (int u = t; u < NBUCK; u += 256) {
    int v = bh[u];
    if (v) atomicAdd(&bcnt[u], v);
  }
}

__global__ void bscan_kernel(const int* __restrict__ bcnt, int* __restrict__ bbase,
                             int* __restrict__ bcursor, int* __restrict__ offsets) {
  __shared__ int sh[1024];
  int t = threadIdx.x;
  int v = (t < NBUCK) ? bcnt[t] : 0;
  sh[t] = v;
  __syncthreads();
  for (int off = 1; off < 1024; off <<= 1) {
    int x = (t >= off) ? sh[t - off] : 0;
    __syncthreads();
    sh[t] += x;
    __syncthreads();
  }
  if (t < NBUCK) {
    bbase[t] = sh[t] - v;
    bcursor[t] = sh[t] - v;
  }
  if (t == NBUCK - 1) {
    bbase[NBUCK] = sh[t];
    offsets[NUM_NODES] = sh[t];  // == NUM_EDGES
  }
}

__global__ __launch_bounds__(256) void bpart_kernel(const int* __restrict__ src,
                                                    const int* __restrict__ dst,
                                                    int* __restrict__ bcursor,
                                                    int2* __restrict__ ebuf) {
  __shared__ int lcnt[NBUCK];
  __shared__ int lbase[NBUCK];
  int t = threadIdx.x;
  for (int u = t; u < NBUCK; u += 256) lcnt[u] = 0;
  __syncthreads();
  int base = blockIdx.x * PA_EDGES;
#pragma unroll
  for (int u = 0; u < PA_EDGES / 256; ++u) {
    int e = base + u * 256 + t;
    if (e < NUM_EDGES) atomicAdd(&lcnt[dst[e] >> BSHIFT], 1);
  }
  __syncthreads();
  for (int u = t; u < NBUCK; u += 256) {
    int v = lcnt[u];
    lbase[u] = v ? atomicAdd(&bcursor[u], v) : 0;
    lcnt[u] = 0;
  }
  __syncthreads();
#pragma unroll
  for (int u = 0; u < PA_EDGES / 256; ++u) {
    int e = base + u * 256 + t;
    if (e < NUM_EDGES) {
      int d = dst[e];
      int b = d >> BSHIFT;
      int p = lbase[b] + atomicAdd(&lcnt[b], 1);
      ebuf[p] = make_int2(src[e], d);
    }
  }
}

// bcsr + degree classification (classify from per-node count v)
__global__ __launch_bounds__(256) void bcsr_kernel(const int2* __restrict__ ebuf,
                                                   const int* __restrict__ bbase,
                                                   int* __restrict__ offsets,
                                                   int* __restrict__ srcs,
                                                   int* __restrict__ gcnt,
                                                   int* __restrict__ Ls,
                                                   int* __restrict__ Lm) {
  __shared__ int ncnt[256];
  __shared__ int sh[256];
  __shared__ int lcur[256];
  __shared__ int c0, c1, b0, b1;
  int b = blockIdx.x;
  int t = threadIdx.x;
  int node0 = b << BSHIFT;
  int ebeg = bbase[b], eend = bbase[b + 1];
  ncnt[t] = 0;
  if (t == 0) { c0 = 0; c1 = 0; }
  __syncthreads();
  for (int i = ebeg + t; i < eend; i += 256)
    atomicAdd(&ncnt[ebuf[i].y - node0], 1);
  __syncthreads();
  int v = ncnt[t];
  sh[t] = v;
  __syncthreads();
  for (int off = 1; off < 256; off <<= 1) {
    int x = (t >= off) ? sh[t - off] : 0;
    __syncthreads();
    sh[t] += x;
    __syncthreads();
  }
  int excl = ebeg + sh[t] - v;
  if (node0 + t < NUM_NODES) offsets[node0 + t] = excl;
  lcur[t] = excl;
  int cls = -1, rank = 0;
  if (node0 + t < NUM_NODES) {
    cls = (v <= 16) ? 0 : 1;
    rank = atomicAdd(cls == 0 ? &c0 : &c1, 1);
  }
  __syncthreads();
  if (t == 0) {
    b0 = atomicAdd(&gcnt[0], c0);
    b1 = atomicAdd(&gcnt[1], c1);
  }
  __syncthreads();
  if (cls == 0) Ls[b0 + rank] = node0 + t;
  else if (cls == 1) Lm[b1 + rank] = node0 + t;
  for (int i = ebeg + t; i < eend; i += 256) {
    int2 ed = ebuf[i];
    int p = atomicAdd(&lcur[ed.y - node0], 1);
    srcs[p] = ed.x;
  }
}

// ---------------- prep: proj1 (block 0) + weight f16 planes (block 1) ----------------
__global__ void prep_kernel(const float* __restrict__ W1, const float* __restrict__ a1,
                            const float* __restrict__ W2,
                            float* __restrict__ w1a, float* __restrict__ w1b,
                            _Float16* __restrict__ w1t_hi, _Float16* __restrict__ w1t_lo,
                            _Float16* __restrict__ w2t_hi, _Float16* __restrict__ w2t_lo) {
  int t = threadIdx.x;
  int h = t >> 6;
  if (blockIdx.x == 0) {
    int k = t & 63;
    float sa = 0.f, sb = 0.f;
    for (int f = 0; f < 64; ++f) {
      float w = W1[(size_t)k * 256 + h * 64 + f];
      sa += w * a1[h * 128 + f];
      sb += w * a1[h * 128 + 64 + f];
    }
    w1a[h * 64 + k] = sa;
    w1b[h * 64 + k] = sb;
  } else {
    int a = t & 63;
    for (int k = 0; k < 64; ++k) {
      float w = W1[(size_t)k * 256 + h * 64 + a] * 256.f;
      _Float16 hi = (_Float16)w;
      w1t_hi[(size_t)(h * 64 + a) * 64 + k] = hi;
      w1t_lo[(size_t)(h * 64 + a) * 64 + k] = (_Float16)(w - (float)hi);
      float v = W2[(size_t)(h * 64 + k) * 64 + a] * 256.f;
      _Float16 hi2 = (_Float16)v;
      w2t_hi[(size_t)(h * 64 + a) * 64 + k] = hi2;
      w2t_lo[(size_t)(h * 64 + a) * 64 + k] = (_Float16)(v - (float)hi2);
    }
  }
}

__device__ __forceinline__ const float* row_ptr(int s, const float* __restrict__ ut,
                                                const float* __restrict__ it) {
  return (s < NUM_USERS) ? ut + (size_t)s * 64 : it + (size_t)(s - NUM_USERS) * 64;
}

__device__ __forceinline__ float lrexp(float x) {
  x = x > 0.f ? x : 0.2f * x;
  return __expf(x);
}

__device__ __forceinline__ float wnorm(float w) {
  float sum = w;
#pragma unroll
  for (int off = 32; off; off >>= 1) sum += __shfl_xor(sum, off, 64);
  return w * (1.f / (sum + 1e-8f));
}

__device__ __forceinline__ void fold4(float4& a) {
#pragma unroll
  for (int off = 16; off <= 32; off <<= 1) {
    a.x += __shfl_xor(a.x, off, 64);
    a.y += __shfl_xor(a.y, off, 64);
    a.z += __shfl_xor(a.z, off, 64);
    a.w += __shfl_xor(a.w, off, 64);
  }
}

__device__ __forceinline__ float elu(float x) {
  return x > 0.f ? x : (__expf(x) - 1.f);
}

// split x*256 into f16 hi + f16 lo (exact pow2 scale keeps lo out of denormals)
__device__ __forceinline__ void split4(float4 o, hf4& hv, hf4& lv) {
  float a0 = o.x * 256.f, a1 = o.y * 256.f, a2 = o.z * 256.f, a3 = o.w * 256.f;
  _Float16 h0 = (_Float16)a0, h1 = (_Float16)a1;
  _Float16 h2 = (_Float16)a2, h3 = (_Float16)a3;
  hv[0] = h0; hv[1] = h1; hv[2] = h2; hv[3] = h3;
  lv[0] = (_Float16)(a0 - (float)h0);
  lv[1] = (_Float16)(a1 - (float)h1);
  lv[2] = (_Float16)(a2 - (float)h2);
  lv[3] = (_Float16)(a3 - (float)h3);
}

__device__ __forceinline__ void splitstore(_Float16* __restrict__ hi,
                                           _Float16* __restrict__ lo,
                                           size_t idx, float v) {
  v *= 256.f;
  _Float16 h = (_Float16)v;
  hi[idx] = h;
  lo[idx] = (_Float16)(v - (float)h);
}

// ---------------- e1 tables: 4 nodes per wave, 16 lanes per node ----------------
__global__ __launch_bounds__(256) void e1g_kernel(
    const float* __restrict__ ut, const float* __restrict__ it,
    const float* __restrict__ w1a, const float* __restrict__ w1b,
    float* __restrict__ e1s, float* __restrict__ e1d) {
  int t = threadIdx.x;
  int wave = t >> 6, lane = t & 63;
  int g = lane >> 4, fl = lane & 15;
  int node = blockIdx.x * 16 + wave * 4 + g;
  bool valid = node < NUM_NODES;
  float4 xv = make_float4(0.f, 0.f, 0.f, 0.f);
  if (valid) xv = *(const float4*)(row_ptr(node, ut, it) + fl * 4);
  float ps[4], pd[4];
#pragma unroll
  for (int h = 0; h < 4; ++h) {
    float4 wa = *(const float4*)(w1a + h * 64 + fl * 4);
    float4 wb = *(const float4*)(w1b + h * 64 + fl * 4);
    ps[h] = xv.x * wa.x + xv.y * wa.y + xv.z * wa.z + xv.w * wa.w;
    pd[h] = xv.x * wb.x + xv.y * wb.y + xv.z * wb.z + xv.w * wb.w;
  }
#pragma unroll
  for (int off = 8; off; off >>= 1) {
#pragma unroll
    for (int h = 0; h < 4; ++h) {
      ps[h] += __shfl_xor(ps[h], off, 16);
      pd[h] += __shfl_xor(pd[h], off, 16);
    }
  }
  if (valid && fl == 0) {
    *(float4*)(e1s + (size_t)node * 4) = make_float4(ps[0], ps[1], ps[2], ps[3]);
    *(float4*)(e1d + (size_t)node * 4) = make_float4(pd[0], pd[1], pd[2], pd[3]);
  }
}

// ---------------- aggregation, small nodes (deg<=16): 4 nodes/wave, 16 lanes/node ------
__global__ __launch_bounds__(256) void aggXs_kernel(
    const int* __restrict__ Ls, const int* __restrict__ gcnt,
    const int* __restrict__ offsets, const int* __restrict__ srcs,
    const float* __restrict__ e1s, const float* __restrict__ e1d,
    const float* __restrict__ ut, const float* __restrict__ it,
    _Float16* __restrict__ aXhi, _Float16* __restrict__ aXlo) {
  __shared__ int sS[4][68];                       // [wave][g*17 + e], pad kills bank clash
  __shared__ __align__(16) float4 sW[4][68];
  const int t = threadIdx.x;
  const int wave = t >> 6, lane = t & 63;
  const int g = lane >> 4, fl = lane & 15;
  const int cnt = gcnt[0];
  const int widx = blockIdx.x * 16 + wave * 4 + g;
  const int node = (widx < cnt) ? Ls[widx] : -1;

  int beg = 0, deg = 0;
  float4 ed = make_float4(0.f, 0.f, 0.f, 0.f);
  if (node >= 0) {
    beg = offsets[node];
    deg = offsets[node + 1] - beg;
    ed = *(const float4*)(e1d + (size_t)node * 4);   // broadcast within group
  }
  int s = 0;
  float w0 = 0.f, w1 = 0.f, w2 = 0.f, w3 = 0.f;
  if (fl < deg) {
    s = srcs[beg + fl];
    float4 ev = *(const float4*)(e1s + (size_t)s * 4);
    w0 = lrexp(ev.x + ed.x);
    w1 = lrexp(ev.y + ed.y);
    w2 = lrexp(ev.z + ed.z);
    w3 = lrexp(ev.w + ed.w);
  }
  float t0 = w0, t1 = w1, t2 = w2, t3 = w3;
#pragma unroll
  for (int off = 8; off; off >>= 1) {
    t0 += __shfl_xor(t0, off, 16);
    t1 += __shfl_xor(t1, off, 16);
    t2 += __shfl_xor(t2, off, 16);
    t3 += __shfl_xor(t3, off, 16);
  }
  w0 *= 1.f / (t0 + 1e-8f);
  w1 *= 1.f / (t1 + 1e-8f);
  w2 *= 1.f / (t2 + 1e-8f);
  w3 *= 1.f / (t3 + 1e-8f);
  sS[wave][g * 17 + fl] = s;
  sW[wave][g * 17 + fl] = make_float4(w0, w1, w2, w3);
  // no barrier needed: same-wave LDS write->read ordered by lgkmcnt

  float4 xr[16];
#pragma unroll
  for (int e = 0; e < 16; ++e) {
    int se = sS[wave][g * 17 + e];                 // broadcast read
    xr[e] = *(const float4*)(row_ptr(se, ut, it) + fl * 4);
  }

  float4 a0 = make_float4(0.f, 0.f, 0.f, 0.f);
  float4 a1 = a0, a2 = a0, a3 = a0;
#pragma unroll
  for (int e = 0; e < 16; ++e) {
    float4 w4 = sW[wave][g * 17 + e];
    float4 xv = xr[e];
    a0.x += w4.x * xv.x; a0.y += w4.x * xv.y; a0.z += w4.x * xv.z; a0.w += w4.x * xv.w;
    a1.x += w4.y * xv.x; a1.y += w4.y * xv.y; a1.z += w4.y * xv.z; a1.w += w4.y * xv.w;
    a2.x += w4.z * xv.x; a2.y += w4.z * xv.y; a2.z += w4.z * xv.z; a2.w += w4.z * xv.w;
    a3.x += w4.w * xv.x; a3.y += w4.w * xv.y; a3.z += w4.w * xv.z; a3.w += w4.w * xv.w;
  }
  if (node >= 0) {
    hf4 hv, lv;
    split4(a0, hv, lv);
    *(hf4*)(aXhi + (size_t)node * 256 + 0 * 64 + fl * 4) = hv;
    *(hf4*)(aXlo + (size_t)node * 256 + 0 * 64 + fl * 4) = lv;
    split4(a1, hv, lv);
    *(hf4*)(aXhi + (size_t)node * 256 + 1 * 64 + fl * 4) = hv;
    *(hf4*)(aXlo + (size_t)node * 256 + 1 * 64 + fl * 4) = lv;
    split4(a2, hv, lv);
    *(hf4*)(aXhi + (size_t)node * 256 + 2 * 64 + fl * 4) = hv;
    *(hf4*)(aXlo + (size_t)node * 256 + 2 * 64 + fl * 4) = lv;
    split4(a3, hv, lv);
    *(hf4*)(aXhi + (size_t)node * 256 + 3 * 64 + fl * 4) = hv;
    *(hf4*)(aXlo + (size_t)node * 256 + 3 * 64 + fl * 4) = lv;
  }
}

// ---------------- aggregation, mid/big nodes (deg>16): 1 node/wave ----------------
__global__ __launch_bounds__(256) void aggXm_kernel(
    const int* __restrict__ Lm, const int* __restrict__ gcnt,
    const int* __restrict__ offsets, const int* __restrict__ srcs,
    const float* __restrict__ e1s, const float* __restrict__ e1d,
    const float* __restrict__ ut, const float* __restrict__ it,
    _Float16* __restrict__ aXhi, _Float16* __restrict__ aXlo) {
  int wid = threadIdx.x >> 6, lane = threadIdx.x & 63;
  int idx = blockIdx.x * 4 + wid;
  if (idx >= gcnt[1]) return;
  int node = Lm[idx];
  int beg = offsets[node], end = offsets[node + 1];
  int deg = end - beg;

  float edv0 = e1d[(size_t)node * 4 + 0];
  float edv1 = e1d[(size_t)node * 4 + 1];
  float edv2 = e1d[(size_t)node * 4 + 2];
  float edv3 = e1d[(size_t)node * 4 + 3];

  if (deg <= 64) {
    int s = 0;
    float w0 = 0.f, w1 = 0.f, w2 = 0.f, w3 = 0.f;
    if (lane < deg) {
      s = srcs[beg + lane];
      float4 ev = *(const float4*)(e1s + (size_t)s * 4);
      w0 = lrexp(ev.x + edv0);
      w1 = lrexp(ev.y + edv1);
      w2 = lrexp(ev.z + edv2);
      w3 = lrexp(ev.w + edv3);
    }
    w0 = wnorm(w0);
    w1 = wnorm(w1);
    w2 = wnorm(w2);
    w3 = wnorm(w3);

    const int g = lane >> 4, fl = lane & 15;
    float4 acc0 = make_float4(0.f, 0.f, 0.f, 0.f);
    float4 acc1 = acc0, acc2 = acc0, acc3 = acc0;
    for (int ebase = 0; ebase < deg; ebase += 16) {
      int i0 = ebase + g, i1 = ebase + 4 + g, i2 = ebase + 8 + g, i3 = ebase + 12 + g;
      int s0 = __shfl(s, i0, 64), s1 = __shfl(s, i1, 64);
      int s2 = __shfl(s, i2, 64), s3 = __shfl(s, i3, 64);
      float4 x0 = *(const float4*)(row_ptr(s0, ut, it) + fl * 4);
      float4 x1 = *(const float4*)(row_ptr(s1, ut, it) + fl * 4);
      float4 x2 = *(const float4*)(row_ptr(s2, ut, it) + fl * 4);
      float4 x3 = *(const float4*)(row_ptr(s3, ut, it) + fl * 4);
#pragma unroll
      for (int j = 0; j < 4; ++j) {
        int ei = ebase + j * 4 + g;
        float4 xv = (j == 0) ? x0 : (j == 1) ? x1 : (j == 2) ? x2 : x3;
        float wg0 = __shfl(w0, ei, 64);
        acc0.x += wg0 * xv.x; acc0.y += wg0 * xv.y;
        acc0.z += wg0 * xv.z; acc0.w += wg0 * xv.w;
        float wg1 = __shfl(w1, ei, 64);
        acc1.x += wg1 * xv.x; acc1.y += wg1 * xv.y;
        acc1.z += wg1 * xv.z; acc1.w += wg1 * xv.w;
        float wg2 = __shfl(w2, ei, 64);
        acc2.x += wg2 * xv.x; acc2.y += wg2 * xv.y;
        acc2.z += wg2 * xv.z; acc2.w += wg2 * xv.w;
        float wg3 = __shfl(w3, ei, 64);
        acc3.x += wg3 * xv.x; acc3.y += wg3 * xv.y;
        acc3.z += wg3 * xv.z; acc3.w += wg3 * xv.w;
      }
    }
    fold4(acc0); fold4(acc1); fold4(acc2); fold4(acc3);

    float4 o = (g == 0) ? acc0 : (g == 1) ? acc1 : (g == 2) ? acc2 : acc3;
    hf4 hv, lv;
    split4(o, hv, lv);
    *(hf4*)(aXhi + (size_t)node * 256 + lane * 4) = hv;
    *(hf4*)(aXlo + (size_t)node * 256 + lane * 4) = lv;
  } else {
    // generic fallback (deg > 64): lane = feature
    float s0 = 0.f, s1 = 0.f, s2 = 0.f, s3 = 0.f;
    for (int e = beg + lane; e < end; e += 64) {
      int s = srcs[e];
      float4 ev = *(const float4*)(e1s + (size_t)s * 4);
      s0 += lrexp(ev.x + edv0); s1 += lrexp(ev.y + edv1);
      s2 += lrexp(ev.z + edv2); s3 += lrexp(ev.w + edv3);
    }
#pragma unroll
    for (int off = 32; off; off >>= 1) {
      s0 += __shfl_xor(s0, off, 64);
      s1 += __shfl_xor(s1, off, 64);
      s2 += __shfl_xor(s2, off, 64);
      s3 += __shfl_xor(s3, off, 64);
    }
    float i0 = 1.f / (s0 + 1e-8f), i1 = 1.f / (s1 + 1e-8f);
    float i2 = 1.f / (s2 + 1e-8f), i3 = 1.f / (s3 + 1e-8f);
    float a0 = 0.f, a1 = 0.f, a2 = 0.f, a3 = 0.f;
    for (int e = beg; e < end; ++e) {
      int sn = srcs[e];
      float xv = row_ptr(sn, ut, it)[lane];
      float4 ev = *(const float4*)(e1s + (size_t)sn * 4);
      a0 += lrexp(ev.x + edv0) * i0 * xv;
      a1 += lrexp(ev.y + edv1) * i1 * xv;
      a2 += lrexp(ev.z + edv2) * i2 * xv;
      a3 += lrexp(ev.w + edv3) * i3 * xv;
    }
    splitstore(aXhi, aXlo, (size_t)node * 256 + 0 * 64 + lane, a0);
    splitstore(aXhi, aXlo, (size_t)node * 256 + 1 * 64 + lane, a1);
    splitstore(aXhi, aXlo, (size_t)node * 256 + 2 * 64 + lane, a2);
    splitstore(aXhi, aXlo, (size_t)node * 256 + 3 * 64 + lane, a3);
  }
}

__device__ __forceinline__ fx4 mfma3(fx4 c, hf8 ah, hf8 al, hf8 bh, hf8 bl) {
  c = __builtin_amdgcn_mfma_f32_16x16x32_f16(ah, bh, c, 0, 0, 0);
  c = __builtin_amdgcn_mfma_f32_16x16x32_f16(al, bh, c, 0, 0, 0);
  c = __builtin_amdgcn_mfma_f32_16x16x32_f16(ah, bl, c, 0, 0, 0);
  return c;
}

// ---------------- dense transform on the MATRIX pipe ----------------
// R9: 16-node tile per wave (was 32) -> grid 2344 blocks, per-wave state halves
// (acc 8 fx4, LDS 4KB/wave). Buys TLP instead of fighting the scheduler for ILP
// (R6-R8 lesson): residency becomes grid-limited ~32 waves/CU vs 8.
__global__ __launch_bounds__(256, 2) void trans_mfma_kernel(
    const _Float16* __restrict__ aXhi, const _Float16* __restrict__ aXlo,
    const _Float16* __restrict__ w1t_hi, const _Float16* __restrict__ w1t_lo,
    const _Float16* __restrict__ w2t_hi, const _Float16* __restrict__ w2t_lo,
    const float* __restrict__ a2v,
    float* __restrict__ h2g, float* __restrict__ e2s, float* __restrict__ e2d) {
  __shared__ __align__(16) _Float16 t1hi[4][16 * 64];
  __shared__ __align__(16) _Float16 t1lo[4][16 * 64];
  const int wave = threadIdx.x >> 6;
  const int l = threadIdx.x & 63;
  const int lr = l & 15, lg = l >> 4;
  const int node0 = (blockIdx.x * 4 + wave) * 16;
  char* myhi = (char*)&t1hi[wave][0];
  char* mylo = (char*)&t1lo[wave][0];
  const float DS = 1.52587890625e-05f;  // 2^-16

  const size_t xbase = (size_t)(node0 + lr) * 256 + lg * 8;

  fx4 acc2[4];
#pragma unroll
  for (int m = 0; m < 4; ++m) acc2[m] = (fx4){0.f, 0.f, 0.f, 0.f};

#pragma unroll 1
  for (int h = 0; h < 4; ++h) {
    // X fragments for this head (one 16-node column)
    hf8 cxh[2], cxl[2];
#pragma unroll
    for (int ks = 0; ks < 2; ++ks) {
      cxh[ks] = *(const hf8*)(aXhi + xbase + h * 64 + ks * 32);
      cxl[ks] = *(const hf8*)(aXlo + xbase + h * 64 + ks * 32);
    }

    fx4 acc1[4];
#pragma unroll
    for (int m = 0; m < 4; ++m) acc1[m] = (fx4){0.f, 0.f, 0.f, 0.f};

    // ---- GEMM1: acc1 = W1h^T @ X^T ----
#pragma unroll
    for (int ks = 0; ks < 2; ++ks) {
      const int ko = ks * 32 + lg * 8;
#pragma unroll
      for (int m = 0; m < 4; ++m) {
        size_t wo = (size_t)((h * 64 + m * 16 + lr) * 64 + ko);
        hf8 wah = *(const hf8*)(w1t_hi + wo);
        hf8 wal = *(const hf8*)(w1t_lo + wo);
        acc1[m] = mfma3(acc1[m], wah, wal, cxh[ks], cxl[ks]);
      }
    }

    // ---- epilogue: scale, ELU, re-split, write t1 planes to LDS ----
    // C1^T layout: row(feat) = m*16 + lg*4 + r, col(node) = lr.
#pragma unroll
    for (int m = 0; m < 4; ++m) {
      hf4 hv, lv;
#pragma unroll
      for (int r = 0; r < 4; ++r) {
        float v = acc1[m][r] * DS;
        v = elu(v) * 256.f;
        _Float16 hi = (_Float16)v;
        hv[r] = hi;
        lv[r] = (_Float16)(v - (float)hi);
      }
      int ro = (m * 32 + lg * 8) ^ ((lr & 7) << 4);
      *(hf4*)(myhi + lr * 128 + ro) = hv;
      *(hf4*)(mylo + lr * 128 + ro) = lv;
    }
    // per-wave LDS slice: same-wave DS FIFO orders write->read, no barrier

    // ---- GEMM2: acc2 += W2h^T @ t1^T ----
#pragma unroll
    for (int ks = 0; ks < 2; ++ks) {
      const int ko = ks * 32 + lg * 8;
      int ro = (ks * 64 + lg * 16) ^ ((lr & 7) << 4);
      hf8 tbh = *(const hf8*)(myhi + lr * 128 + ro);
      hf8 tbl = *(const hf8*)(mylo + lr * 128 + ro);
#pragma unroll
      for (int m = 0; m < 4; ++m) {
        size_t wo = (size_t)((h * 64 + m * 16 + lr) * 64 + ko);
        hf8 wah = *(const hf8*)(w2t_hi + wo);
        hf8 wal = *(const hf8*)(w2t_lo + wo);
        acc2[m] = mfma3(acc2[m], wah, wal, tbh, tbl);
      }
    }
  }

  // ---- h2 store + e2s/e2d dots ----
  // C2^T layout: row(out) = m*16 + lg*4 + r, col(node) = lr.
  float ps = 0.f, pd = 0.f;
  int node = node0 + lr;
#pragma unroll
  for (int m = 0; m < 4; ++m) {
    fx4 al = *(const fx4*)(a2v + m * 16 + lg * 4);
    fx4 ar = *(const fx4*)(a2v + 64 + m * 16 + lg * 4);
    fx4 v = acc2[m] * DS;
    if (node < NUM_NODES)
      *(fx4*)(h2g + (size_t)node * 64 + m * 16 + lg * 4) = v;
    ps += v[0] * al[0] + v[1] * al[1] + v[2] * al[2] + v[3] * al[3];
    pd += v[0] * ar[0] + v[1] * ar[1] + v[2] * ar[2] + v[3] * ar[3];
  }
  ps += __shfl_xor(ps, 16, 64);
  ps += __shfl_xor(ps, 32, 64);
  pd += __shfl_xor(pd, 16, 64);
  pd += __shfl_xor(pd, 32, 64);
  if (lg == 0 && node < NUM_NODES) {
    e2s[node] = ps;
    e2d[node] = pd;
  }
}

// ---------------- layer-2 aggregation + residual ----------------
__global__ __launch_bounds__(256) void agg2_kernel(
    const int* __restrict__ offsets, const int* __restrict__ srcs,
    const float* __restrict__ e2s, const float* __restrict__ e2d,
    const int* __restrict__ nodelist, const float* __restrict__ h2,
    const float* __restrict__ ut, const float* __restrict__ it,
    float* __restrict__ hfin) {
  int wid = threadIdx.x >> 6, lane = threadIdx.x & 63;
  int idx = blockIdx.x * 4 + wid;
  if (idx >= 2 * BATCH) return;
  int node = nodelist[idx];
  int beg = offsets[node], end = offsets[node + 1];
  int deg = end - beg;
  float edv = e2d[node];

  if (deg <= 64) {
    int s = 0;
    float w = 0.f;
    if (lane < deg) {
      s = srcs[beg + lane];
      w = lrexp(e2s[s] + edv);
    }
    w = wnorm(w);

    const int g = lane >> 4, fl = lane & 15;
    float4 acc = make_float4(0.f, 0.f, 0.f, 0.f);
#pragma unroll 4
    for (int e = 0; e < deg; e += 4) {
      int ei = e + g;
      int sg = __shfl(s, ei, 64);
      float wg = __shfl(w, ei, 64);
      float4 hv = *(const float4*)(h2 + (size_t)sg * 64 + fl * 4);
      acc.x += wg * hv.x; acc.y += wg * hv.y; acc.z += wg * hv.z; acc.w += wg * hv.w;
    }
    fold4(acc);
    if (g == 0) {
      const float* rp = (node < NUM_USERS) ? ut + (size_t)node * 64
                                           : it + (size_t)(node - NUM_USERS) * 64;
      float4 res = *(const float4*)(rp + fl * 4);
      acc.x += res.x; acc.y += res.y; acc.z += res.z; acc.w += res.w;
      *(float4*)(hfin + (size_t)node * 64 + fl * 4) = acc;
    }
  } else {
    float psum = 0.f;
    for (int e = beg + lane; e < end; e += 64) {
      int s = srcs[e];
      psum += lrexp(e2s[s] + edv);
    }
#pragma unroll
    for (int off = 32; off; off >>= 1) psum += __shfl_xor(psum, off, 64);
    float inv = 1.f / (psum + 1e-8f);
    float acc = 0.f;
    for (int e = beg; e < end; ++e) {
      int s0 = srcs[e];
      acc += lrexp(e2s[s0] + edv) * inv * h2[(size_t)s0 * 64 + lane];
    }
    float res = (node < NUM_USERS) ? ut[(size_t)node * 64 + lane]
                                   : it[(size_t)(node - NUM_USERS) * 64 + lane];
    hfin[(size_t)node * 64 + lane] = acc + res;
  }
}

// ---------------- final batched dot ----------------
__global__ __launch_bounds__(256) void final_kernel(
    const float* __restrict__ hf, const int* __restrict__ uid,
    const int* __restrict__ iid, float* __restrict__ out) {
  int wid = threadIdx.x >> 6, lane = threadIdx.x & 63;
  int idx = blockIdx.x * 4 + wid;
  if (idx >= BATCH) return;
  int u = uid[idx], v = iid[idx];
  float a = hf[(size_t)u * 64 + lane];
  float b = hf[(size_t)(NUM_USERS + v) * 64 + lane];
  float p = a * b;
#pragma unroll
  for (int off = 32; off; off >>= 1) p += __shfl_xor(p, off, 64);
  if (lane == 0) out[idx] = p;
}

extern "C" void kernel_launch(void* const* d_in, const int* in_sizes, int n_in,
                              void* d_out, int out_size, void* d_ws, size_t ws_size,
                              hipStream_t stream) {
  const float* user_table = (const float*)d_in[0];
  const float* item_table = (const float*)d_in[1];
  const float* W1 = (const float*)d_in[2];
  const float* a1 = (const float*)d_in[3];
  const float* W2 = (const float*)d_in[4];
  const float* a2 = (const float*)d_in[5];
  const int* edge_index = (const int*)d_in[6];
  const int* user_ids = (const int*)d_in[7];
  const int* item_ids = (const int*)d_in[8];
  float* out = (float*)d_out;

  const int* src = edge_index;
  const int* dst = edge_index + NUM_EDGES;

  // ---- workspace layout (elements) ----
  float* ws = (float*)d_ws;
  size_t off = 0;
  auto falloc = [&](size_t n) { float* p = ws + off; off += n; return p; };
  float* h2  = falloc((size_t)NUM_NODES * 64);
  float* e1s = falloc((size_t)NUM_NODES * 4);
  float* e1d = falloc((size_t)NUM_NODES * 4);
  float* e2s = falloc(NUM_NODES);
  float* e2d = falloc(NUM_NODES);
  float* w1a = falloc(256);
  float* w1b = falloc(256);
  int* offsets  = (int*)falloc(NUM_NODES + 1);
  int* srcs     = (int*)falloc(NUM_EDGES);
  int* nodelist = (int*)falloc(2 * BATCH);
  int* bcnt     = (int*)falloc(NBUCK);
  int* bbase    = (int*)falloc(NBUCK + 1);
  int* bcursor  = (int*)falloc(NBUCK);
  int* gcnt     = (int*)falloc(2);
  int* Ls       = (int*)falloc(NNPAD);
  int* Lm       = (int*)falloc(NNPAD);
  off = (off + 3) & ~(size_t)3;  // 16B-align the f16 planes
  _Float16* aggXhi = (_Float16*)(ws + off); off += (size_t)NNPAD * 128;
  _Float16* aggXlo = (_Float16*)(ws + off); off += (size_t)NNPAD * 128;

  // ebuf (16 MB) aliases plane head — dead before aggX writes (pad rows at +76.8MB safe).
  int2* ebuf = (int2*)aggXhi;
  // hfin aliases plane head — aggX planes dead after trans_mfma reads.
  float* hfin = (float*)aggXhi;
  // weight f16 planes: fresh allocation (128 KB), no lifetime conflicts
  _Float16* w1t_hi = (_Float16*)falloc(4 * 64 * 64 / 2 + 16);
  _Float16* w1t_lo = (_Float16*)falloc(4 * 64 * 64 / 2 + 16);
  _Float16* w2t_hi = (_Float16*)falloc(4 * 64 * 64 / 2 + 16);
  _Float16* w2t_lo = (_Float16*)falloc(4 * 64 * 64 / 2 + 16);

  flag_kernel<<<(BATCH + 255) / 256, 256, 0, stream>>>(user_ids, item_ids,
                                                       nodelist, bcnt, gcnt,
                                                       aggXhi, aggXlo);
  bhist_kernel<<<PA_BLOCKS, 256, 0, stream>>>(dst, bcnt);
  bscan_kernel<<<1, 1024, 0, stream>>>(bcnt, bbase, bcursor, offsets);
  bpart_kernel<<<PA_BLOCKS, 256, 0, stream>>>(src, dst, bcursor, ebuf);
  bcsr_kernel<<<NBUCK, 256, 0, stream>>>(ebuf, bbase, offsets, srcs,
                                         gcnt, Ls, Lm);

  prep_kernel<<<2, 256, 0, stream>>>(W1, a1, W2, w1a, w1b,
                                     w1t_hi, w1t_lo, w2t_hi, w2t_lo);
  e1g_kernel<<<(NNPAD + 15) / 16, 256, 0, stream>>>(user_table, item_table,
                                                    w1a, w1b, e1s, e1d);

  aggXs_kernel<<<(NNPAD + 15) / 16, 256, 0, stream>>>(Ls, gcnt, offsets, srcs,
                                                      e1s, e1d, user_table,
                                                      item_table, aggXhi, aggXlo);
  aggXm_kernel<<<(NNPAD + 3) / 4, 256, 0, stream>>>(Lm, gcnt, offsets, srcs,
                                                    e1s, e1d, user_table,
                                                    item_table, aggXhi, aggXlo);
  trans_mfma_kernel<<<TBLK3, 256, 0, stream>>>(aggXhi, aggXlo,
                                               w1t_hi, w1t_lo, w2t_hi, w2t_lo,
                                               a2, h2, e2s, e2d);

  agg2_kernel<<<(2 * BATCH + 3) / 4, 256, 0, stream>>>(offsets, srcs, e2s, e2d,
                                                       nodelist, h2,
                                                       user_table, item_table, hfin);
  final_kernel<<<(BATCH + 3) / 4, 256, 0, stream>>>(hfin, user_ids, item_ids, out);
}

// Round 11
// 489.363 us; speedup vs baseline: 1.1601x; 1.1601x over previous
//
#include <hip/hip_runtime.h>
#include <cstdint>
#include <cstddef>

#define NUM_USERS 100000
#define NUM_ITEMS 50000
#define NUM_NODES 150000
#define NUM_EDGES 2000000
#define BATCH 16384
#define BSHIFT 8                                   // 256 nodes per bucket
#define NBUCK ((NUM_NODES + 255) >> BSHIFT)        // 586 buckets
#define PA_EDGES 8192                              // edges per block, bhist/bpart
#define PA_BLOCKS ((NUM_EDGES + PA_EDGES - 1) / PA_EDGES)  // 245
#define NNPAD 150016                               // NUM_NODES rounded to 128
#define TBLK2 (NNPAD / 128)                        // 1172 blocks (4 waves x 32 nodes)
#define AGG_MBLK ((NNPAD + 3) / 4)                 // mid-path blocks (1 node/wave)
#define AGG_SBLK ((NNPAD + 15) / 16)               // small-path blocks (4 nodes/wave)

typedef _Float16 hf8 __attribute__((ext_vector_type(8)));
typedef _Float16 hf4 __attribute__((ext_vector_type(4)));
typedef float fx4 __attribute__((ext_vector_type(4)));

// ---------------- setup: nodelist + counters zero + aggX pad-row zero ----------------
__global__ void flag_kernel(const int* __restrict__ uid, const int* __restrict__ iid,
                            int* __restrict__ nodelist, int* __restrict__ bcnt,
                            int* __restrict__ gcnt,
                            _Float16* __restrict__ aXhi, _Float16* __restrict__ aXlo) {
  int i = blockIdx.x * blockDim.x + threadIdx.x;
  if (i < NBUCK) bcnt[i] = 0;
  if (i < 2) gcnt[i] = 0;
  // zero the 16 pad rows (NNPAD - NUM_NODES) of both f16 planes: 2048 floats each.
  if (i < 2048) {
    ((float*)(aXhi + (size_t)NUM_NODES * 256))[i] = 0.f;
    ((float*)(aXlo + (size_t)NUM_NODES * 256))[i] = 0.f;
  }
  if (i < BATCH) {
    nodelist[2 * i] = uid[i];
    nodelist[2 * i + 1] = NUM_USERS + iid[i];
  }
}

// ---------------- bucketed CSR construction ----------------
__global__ __launch_bounds__(256) void bhist_kernel(const int* __restrict__ dst,
                                                    int* __restrict__ bcnt) {
  __shared__ int bh[NBUCK];
  int t = threadIdx.x;
  for (int u = t; u < NBUCK; u += 256) bh[u] = 0;
  __syncthreads();
  int base = blockIdx.x * PA_EDGES;
#pragma unroll
  for (int u = 0; u < PA_EDGES / 256; ++u) {
    int e = base + u * 256 + t;
    if (e < NUM_EDGES) atomicAdd(&bh[dst[e] >> BSHIFT], 1);
  }
  __syncthreads();
  for (int u = t; u < NBUCK; u += 256) {
    int v = bh[u];
    if (v) atomicAdd(&bcnt[u], v);
  }
}

__global__ void bscan_kernel(const int* __restrict__ bcnt, int* __restrict__ bbase,
                             int* __restrict__ bcursor, int* __restrict__ offsets) {
  __shared__ int sh[1024];
  int t = threadIdx.x;
  int v = (t < NBUCK) ? bcnt[t] : 0;
  sh[t] = v;
  __syncthreads();
  for (int off = 1; off < 1024; off <<= 1) {
    int x = (t >= off) ? sh[t - off] : 0;
    __syncthreads();
    sh[t] += x;
    __syncthreads();
  }
  if (t < NBUCK) {
    bbase[t] = sh[t] - v;
    bcursor[t] = sh[t] - v;
  }
  if (t == NBUCK - 1) {
    bbase[NBUCK] = sh[t];
    offsets[NUM_NODES] = sh[t];  // == NUM_EDGES
  }
}

__global__ __launch_bounds__(256) void bpart_kernel(const int* __restrict__ src,
                                                    const int* __restrict__ dst,
                                                    int* __restrict__ bcursor,
                                                    int2* __restrict__ ebuf) {
  __shared__ int lcnt[NBUCK];
  __shared__ int lbase[NBUCK];
  int t = threadIdx.x;
  for (int u = t; u < NBUCK; u += 256) lcnt[u] = 0;
  __syncthreads();
  int base = blockIdx.x * PA_EDGES;
#pragma unroll
  for (int u = 0; u < PA_EDGES / 256; ++u) {
    int e = base + u * 256 + t;
    if (e < NUM_EDGES) atomicAdd(&lcnt[dst[e] >> BSHIFT], 1);
  }
  __syncthreads();
  for (int u = t; u < NBUCK; u += 256) {
    int v = lcnt[u];
    lbase[u] = v ? atomicAdd(&bcursor[u], v) : 0;
    lcnt[u] = 0;
  }
  __syncthreads();
#pragma unroll
  for (int u = 0; u < PA_EDGES / 256; ++u) {
    int e = base + u * 256 + t;
    if (e < NUM_EDGES) {
      int d = dst[e];
      int b = d >> BSHIFT;
      int p = lbase[b] + atomicAdd(&lcnt[b], 1);
      ebuf[p] = make_int2(src[e], d);
    }
  }
}

// bcsr + degree classification (classify from per-node count v)
__global__ __launch_bounds__(256) void bcsr_kernel(const int2* __restrict__ ebuf,
                                                   const int* __restrict__ bbase,
                                                   int* __restrict__ offsets,
                                                   int* __restrict__ srcs,
                                                   int* __restrict__ gcnt,
                                                   int* __restrict__ Ls,
                                                   int* __restrict__ Lm) {
  __shared__ int ncnt[256];
  __shared__ int sh[256];
  __shared__ int lcur[256];
  __shared__ int c0, c1, b0, b1;
  int b = blockIdx.x;
  int t = threadIdx.x;
  int node0 = b << BSHIFT;
  int ebeg = bbase[b], eend = bbase[b + 1];
  ncnt[t] = 0;
  if (t == 0) { c0 = 0; c1 = 0; }
  __syncthreads();
  for (int i = ebeg + t; i < eend; i += 256)
    atomicAdd(&ncnt[ebuf[i].y - node0], 1);
  __syncthreads();
  int v = ncnt[t];
  sh[t] = v;
  __syncthreads();
  for (int off = 1; off < 256; off <<= 1) {
    int x = (t >= off) ? sh[t - off] : 0;
    __syncthreads();
    sh[t] += x;
    __syncthreads();
  }
  int excl = ebeg + sh[t] - v;
  if (node0 + t < NUM_NODES) offsets[node0 + t] = excl;
  lcur[t] = excl;
  int cls = -1, rank = 0;
  if (node0 + t < NUM_NODES) {
    cls = (v <= 16) ? 0 : 1;
    rank = atomicAdd(cls == 0 ? &c0 : &c1, 1);
  }
  __syncthreads();
  if (t == 0) {
    b0 = atomicAdd(&gcnt[0], c0);
    b1 = atomicAdd(&gcnt[1], c1);
  }
  __syncthreads();
  if (cls == 0) Ls[b0 + rank] = node0 + t;
  else if (cls == 1) Lm[b1 + rank] = node0 + t;
  for (int i = ebeg + t; i < eend; i += 256) {
    int2 ed = ebuf[i];
    int p = atomicAdd(&lcur[ed.y - node0], 1);
    srcs[p] = ed.x;
  }
}

// ---------------- prep: proj1 (block 0) + weight f16 planes (block 1) ----------------
__global__ void prep_kernel(const float* __restrict__ W1, const float* __restrict__ a1,
                            const float* __restrict__ W2,
                            float* __restrict__ w1a, float* __restrict__ w1b,
                            _Float16* __restrict__ w1t_hi, _Float16* __restrict__ w1t_lo,
                            _Float16* __restrict__ w2t_hi, _Float16* __restrict__ w2t_lo) {
  int t = threadIdx.x;
  int h = t >> 6;
  if (blockIdx.x == 0) {
    int k = t & 63;
    float sa = 0.f, sb = 0.f;
    for (int f = 0; f < 64; ++f) {
      float w = W1[(size_t)k * 256 + h * 64 + f];
      sa += w * a1[h * 128 + f];
      sb += w * a1[h * 128 + 64 + f];
    }
    w1a[h * 64 + k] = sa;
    w1b[h * 64 + k] = sb;
  } else {
    int a = t & 63;
    for (int k = 0; k < 64; ++k) {
      float w = W1[(size_t)k * 256 + h * 64 + a] * 256.f;
      _Float16 hi = (_Float16)w;
      w1t_hi[(size_t)(h * 64 + a) * 64 + k] = hi;
      w1t_lo[(size_t)(h * 64 + a) * 64 + k] = (_Float16)(w - (float)hi);
      float v = W2[(size_t)(h * 64 + k) * 64 + a] * 256.f;
      _Float16 hi2 = (_Float16)v;
      w2t_hi[(size_t)(h * 64 + a) * 64 + k] = hi2;
      w2t_lo[(size_t)(h * 64 + a) * 64 + k] = (_Float16)(v - (float)hi2);
    }
  }
}

__device__ __forceinline__ const float* row_ptr(int s, const float* __restrict__ ut,
                                                const float* __restrict__ it) {
  return (s < NUM_USERS) ? ut + (size_t)s * 64 : it + (size_t)(s - NUM_USERS) * 64;
}

__device__ __forceinline__ float lrexp(float x) {
  x = x > 0.f ? x : 0.2f * x;
  return __expf(x);
}

__device__ __forceinline__ float wnorm(float w) {
  float sum = w;
#pragma unroll
  for (int off = 32; off; off >>= 1) sum += __shfl_xor(sum, off, 64);
  return w * (1.f / (sum + 1e-8f));
}

__device__ __forceinline__ void fold4(float4& a) {
#pragma unroll
  for (int off = 16; off <= 32; off <<= 1) {
    a.x += __shfl_xor(a.x, off, 64);
    a.y += __shfl_xor(a.y, off, 64);
    a.z += __shfl_xor(a.z, off, 64);
    a.w += __shfl_xor(a.w, off, 64);
  }
}

__device__ __forceinline__ float elu(float x) {
  return x > 0.f ? x : (__expf(x) - 1.f);
}

// split x*256 into f16 hi + f16 lo (exact pow2 scale keeps lo out of denormals)
__device__ __forceinline__ void split4(float4 o, hf4& hv, hf4& lv) {
  float a0 = o.x * 256.f, a1 = o.y * 256.f, a2 = o.z * 256.f, a3 = o.w * 256.f;
  _Float16 h0 = (_Float16)a0, h1 = (_Float16)a1;
  _Float16 h2 = (_Float16)a2, h3 = (_Float16)a3;
  hv[0] = h0; hv[1] = h1; hv[2] = h2; hv[3] = h3;
  lv[0] = (_Float16)(a0 - (float)h0);
  lv[1] = (_Float16)(a1 - (float)h1);
  lv[2] = (_Float16)(a2 - (float)h2);
  lv[3] = (_Float16)(a3 - (float)h3);
}

__device__ __forceinline__ void splitstore(_Float16* __restrict__ hi,
                                           _Float16* __restrict__ lo,
                                           size_t idx, float v) {
  v *= 256.f;
  _Float16 h = (_Float16)v;
  hi[idx] = h;
  lo[idx] = (_Float16)(v - (float)h);
}

// ---------------- e1 tables: 4 nodes per wave, 16 lanes per node ----------------
__global__ __launch_bounds__(256) void e1g_kernel(
    const float* __restrict__ ut, const float* __restrict__ it,
    const float* __restrict__ w1a, const float* __restrict__ w1b,
    float* __restrict__ e1s, float* __restrict__ e1d) {
  int t = threadIdx.x;
  int wave = t >> 6, lane = t & 63;
  int g = lane >> 4, fl = lane & 15;
  int node = blockIdx.x * 16 + wave * 4 + g;
  bool valid = node < NUM_NODES;
  float4 xv = make_float4(0.f, 0.f, 0.f, 0.f);
  if (valid) xv = *(const float4*)(row_ptr(node, ut, it) + fl * 4);
  float ps[4], pd[4];
#pragma unroll
  for (int h = 0; h < 4; ++h) {
    float4 wa = *(const float4*)(w1a + h * 64 + fl * 4);
    float4 wb = *(const float4*)(w1b + h * 64 + fl * 4);
    ps[h] = xv.x * wa.x + xv.y * wa.y + xv.z * wa.z + xv.w * wa.w;
    pd[h] = xv.x * wb.x + xv.y * wb.y + xv.z * wb.z + xv.w * wb.w;
  }
#pragma unroll
  for (int off = 8; off; off >>= 1) {
#pragma unroll
    for (int h = 0; h < 4; ++h) {
      ps[h] += __shfl_xor(ps[h], off, 16);
      pd[h] += __shfl_xor(pd[h], off, 16);
    }
  }
  if (valid && fl == 0) {
    *(float4*)(e1s + (size_t)node * 4) = make_float4(ps[0], ps[1], ps[2], ps[3]);
    *(float4*)(e1d + (size_t)node * 4) = make_float4(pd[0], pd[1], pd[2], pd[3]);
  }
}

// ---------------- merged aggregation: mid blocks first (stragglers start early),
// then small blocks. Bodies identical to the twice-verified R8 kernels. ----------------
__global__ __launch_bounds__(256) void aggX_kernel(
    const int* __restrict__ Ls, const int* __restrict__ Lm,
    const int* __restrict__ gcnt,
    const int* __restrict__ offsets, const int* __restrict__ srcs,
    const float* __restrict__ e1s, const float* __restrict__ e1d,
    const float* __restrict__ ut, const float* __restrict__ it,
    _Float16* __restrict__ aXhi, _Float16* __restrict__ aXlo) {
  __shared__ int sS[4][68];                       // [wave][g*17 + e] (small path)
  __shared__ __align__(16) float4 sW[4][68];
  const int t = threadIdx.x;
  const int wave = t >> 6, lane = t & 63;
  const int g = lane >> 4, fl = lane & 15;

  if (blockIdx.x < AGG_MBLK) {
    // ---------- mid/big path (deg>16): 1 node/wave ----------
    int idx = blockIdx.x * 4 + wave;
    if (idx >= gcnt[1]) return;
    int node = Lm[idx];
    int beg = offsets[node], end = offsets[node + 1];
    int deg = end - beg;

    float edv0 = e1d[(size_t)node * 4 + 0];
    float edv1 = e1d[(size_t)node * 4 + 1];
    float edv2 = e1d[(size_t)node * 4 + 2];
    float edv3 = e1d[(size_t)node * 4 + 3];

    if (deg <= 64) {
      int s = 0;
      float w0 = 0.f, w1 = 0.f, w2 = 0.f, w3 = 0.f;
      if (lane < deg) {
        s = srcs[beg + lane];
        float4 ev = *(const float4*)(e1s + (size_t)s * 4);
        w0 = lrexp(ev.x + edv0);
        w1 = lrexp(ev.y + edv1);
        w2 = lrexp(ev.z + edv2);
        w3 = lrexp(ev.w + edv3);
      }
      w0 = wnorm(w0);
      w1 = wnorm(w1);
      w2 = wnorm(w2);
      w3 = wnorm(w3);

      float4 acc0 = make_float4(0.f, 0.f, 0.f, 0.f);
      float4 acc1 = acc0, acc2 = acc0, acc3 = acc0;
      for (int ebase = 0; ebase < deg; ebase += 16) {
        int i0 = ebase + g, i1 = ebase + 4 + g, i2 = ebase + 8 + g, i3 = ebase + 12 + g;
        int s0 = __shfl(s, i0, 64), s1 = __shfl(s, i1, 64);
        int s2 = __shfl(s, i2, 64), s3 = __shfl(s, i3, 64);
        float4 x0 = *(const float4*)(row_ptr(s0, ut, it) + fl * 4);
        float4 x1 = *(const float4*)(row_ptr(s1, ut, it) + fl * 4);
        float4 x2 = *(const float4*)(row_ptr(s2, ut, it) + fl * 4);
        float4 x3 = *(const float4*)(row_ptr(s3, ut, it) + fl * 4);
#pragma unroll
        for (int j = 0; j < 4; ++j) {
          int ei = ebase + j * 4 + g;
          float4 xv = (j == 0) ? x0 : (j == 1) ? x1 : (j == 2) ? x2 : x3;
          float wg0 = __shfl(w0, ei, 64);
          acc0.x += wg0 * xv.x; acc0.y += wg0 * xv.y;
          acc0.z += wg0 * xv.z; acc0.w += wg0 * xv.w;
          float wg1 = __shfl(w1, ei, 64);
          acc1.x += wg1 * xv.x; acc1.y += wg1 * xv.y;
          acc1.z += wg1 * xv.z; acc1.w += wg1 * xv.w;
          float wg2 = __shfl(w2, ei, 64);
          acc2.x += wg2 * xv.x; acc2.y += wg2 * xv.y;
          acc2.z += wg2 * xv.z; acc2.w += wg2 * xv.w;
          float wg3 = __shfl(w3, ei, 64);
          acc3.x += wg3 * xv.x; acc3.y += wg3 * xv.y;
          acc3.z += wg3 * xv.z; acc3.w += wg3 * xv.w;
        }
      }
      fold4(acc0); fold4(acc1); fold4(acc2); fold4(acc3);

      float4 o = (g == 0) ? acc0 : (g == 1) ? acc1 : (g == 2) ? acc2 : acc3;
      hf4 hv, lv;
      split4(o, hv, lv);
      *(hf4*)(aXhi + (size_t)node * 256 + lane * 4) = hv;
      *(hf4*)(aXlo + (size_t)node * 256 + lane * 4) = lv;
    } else {
      // generic fallback (deg > 64): lane = feature
      float s0 = 0.f, s1 = 0.f, s2 = 0.f, s3 = 0.f;
      for (int e = beg + lane; e < end; e += 64) {
        int s = srcs[e];
        float4 ev = *(const float4*)(e1s + (size_t)s * 4);
        s0 += lrexp(ev.x + edv0); s1 += lrexp(ev.y + edv1);
        s2 += lrexp(ev.z + edv2); s3 += lrexp(ev.w + edv3);
      }
#pragma unroll
      for (int off = 32; off; off >>= 1) {
        s0 += __shfl_xor(s0, off, 64);
        s1 += __shfl_xor(s1, off, 64);
        s2 += __shfl_xor(s2, off, 64);
        s3 += __shfl_xor(s3, off, 64);
      }
      float i0 = 1.f / (s0 + 1e-8f), i1 = 1.f / (s1 + 1e-8f);
      float i2 = 1.f / (s2 + 1e-8f), i3 = 1.f / (s3 + 1e-8f);
      float a0 = 0.f, a1 = 0.f, a2 = 0.f, a3 = 0.f;
      for (int e = beg; e < end; ++e) {
        int sn = srcs[e];
        float xv = row_ptr(sn, ut, it)[lane];
        float4 ev = *(const float4*)(e1s + (size_t)sn * 4);
        a0 += lrexp(ev.x + edv0) * i0 * xv;
        a1 += lrexp(ev.y + edv1) * i1 * xv;
        a2 += lrexp(ev.z + edv2) * i2 * xv;
        a3 += lrexp(ev.w + edv3) * i3 * xv;
      }
      splitstore(aXhi, aXlo, (size_t)node * 256 + 0 * 64 + lane, a0);
      splitstore(aXhi, aXlo, (size_t)node * 256 + 1 * 64 + lane, a1);
      splitstore(aXhi, aXlo, (size_t)node * 256 + 2 * 64 + lane, a2);
      splitstore(aXhi, aXlo, (size_t)node * 256 + 3 * 64 + lane, a3);
    }
    return;
  }

  // ---------- small path (deg<=16): 4 nodes/wave, 16 lanes/node ----------
  const int cnt = gcnt[0];
  const int widx = (blockIdx.x - AGG_MBLK) * 16 + wave * 4 + g;
  const int node = (widx < cnt) ? Ls[widx] : -1;

  int beg = 0, deg = 0;
  float4 ed = make_float4(0.f, 0.f, 0.f, 0.f);
  if (node >= 0) {
    beg = offsets[node];
    deg = offsets[node + 1] - beg;
    ed = *(const float4*)(e1d + (size_t)node * 4);   // broadcast within group
  }
  int s = 0;
  float w0 = 0.f, w1 = 0.f, w2 = 0.f, w3 = 0.f;
  if (fl < deg) {
    s = srcs[beg + fl];
    float4 ev = *(const float4*)(e1s + (size_t)s * 4);
    w0 = lrexp(ev.x + ed.x);
    w1 = lrexp(ev.y + ed.y);
    w2 = lrexp(ev.z + ed.z);
    w3 = lrexp(ev.w + ed.w);
  }
  float t0 = w0, t1 = w1, t2 = w2, t3 = w3;
#pragma unroll
  for (int off = 8; off; off >>= 1) {
    t0 += __shfl_xor(t0, off, 16);
    t1 += __shfl_xor(t1, off, 16);
    t2 += __shfl_xor(t2, off, 16);
    t3 += __shfl_xor(t3, off, 16);
  }
  w0 *= 1.f / (t0 + 1e-8f);
  w1 *= 1.f / (t1 + 1e-8f);
  w2 *= 1.f / (t2 + 1e-8f);
  w3 *= 1.f / (t3 + 1e-8f);
  sS[wave][g * 17 + fl] = s;
  sW[wave][g * 17 + fl] = make_float4(w0, w1, w2, w3);
  // no barrier needed: same-wave LDS write->read ordered by lgkmcnt

  float4 xr[16];
#pragma unroll
  for (int e = 0; e < 16; ++e) {
    int se = sS[wave][g * 17 + e];                 // broadcast read
    xr[e] = *(const float4*)(row_ptr(se, ut, it) + fl * 4);
  }

  float4 a0 = make_float4(0.f, 0.f, 0.f, 0.f);
  float4 a1 = a0, a2 = a0, a3 = a0;
#pragma unroll
  for (int e = 0; e < 16; ++e) {
    float4 w4 = sW[wave][g * 17 + e];
    float4 xv = xr[e];
    a0.x += w4.x * xv.x; a0.y += w4.x * xv.y; a0.z += w4.x * xv.z; a0.w += w4.x * xv.w;
    a1.x += w4.y * xv.x; a1.y += w4.y * xv.y; a1.z += w4.y * xv.z; a1.w += w4.y * xv.w;
    a2.x += w4.z * xv.x; a2.y += w4.z * xv.y; a2.z += w4.z * xv.z; a2.w += w4.z * xv.w;
    a3.x += w4.w * xv.x; a3.y += w4.w * xv.y; a3.z += w4.w * xv.z; a3.w += w4.w * xv.w;
  }
  if (node >= 0) {
    hf4 hv, lv;
    split4(a0, hv, lv);
    *(hf4*)(aXhi + (size_t)node * 256 + 0 * 64 + fl * 4) = hv;
    *(hf4*)(aXlo + (size_t)node * 256 + 0 * 64 + fl * 4) = lv;
    split4(a1, hv, lv);
    *(hf4*)(aXhi + (size_t)node * 256 + 1 * 64 + fl * 4) = hv;
    *(hf4*)(aXlo + (size_t)node * 256 + 1 * 64 + fl * 4) = lv;
    split4(a2, hv, lv);
    *(hf4*)(aXhi + (size_t)node * 256 + 2 * 64 + fl * 4) = hv;
    *(hf4*)(aXlo + (size_t)node * 256 + 2 * 64 + fl * 4) = lv;
    split4(a3, hv, lv);
    *(hf4*)(aXhi + (size_t)node * 256 + 3 * 64 + fl * 4) = hv;
    *(hf4*)(aXlo + (size_t)node * 256 + 3 * 64 + fl * 4) = lv;
  }
}

__device__ __forceinline__ fx4 mfma3(fx4 c, hf8 ah, hf8 al, hf8 bh, hf8 bl) {
  c = __builtin_amdgcn_mfma_f32_16x16x32_f16(ah, bh, c, 0, 0, 0);
  c = __builtin_amdgcn_mfma_f32_16x16x32_f16(al, bh, c, 0, 0, 0);
  c = __builtin_amdgcn_mfma_f32_16x16x32_f16(ah, bl, c, 0, 0, 0);
  return c;
}

// ---------------- dense transform on the MATRIX pipe (R8 version, reverted) ----------
__global__ __launch_bounds__(256, 2) void trans_mfma_kernel(
    const _Float16* __restrict__ aXhi, const _Float16* __restrict__ aXlo,
    const _Float16* __restrict__ w1t_hi, const _Float16* __restrict__ w1t_lo,
    const _Float16* __restrict__ w2t_hi, const _Float16* __restrict__ w2t_lo,
    const float* __restrict__ a2v,
    float* __restrict__ h2g, float* __restrict__ e2s, float* __restrict__ e2d) {
  __shared__ __align__(16) _Float16 t1hi[4][32 * 64];
  __shared__ __align__(16) _Float16 t1lo[4][32 * 64];
  const int wave = threadIdx.x >> 6;
  const int l = threadIdx.x & 63;
  const int lr = l & 15, lg = l >> 4;
  const int node0 = (blockIdx.x * 4 + wave) * 32;
  char* myhi = (char*)&t1hi[wave][0];
  char* mylo = (char*)&t1lo[wave][0];
  const float DS = 1.52587890625e-05f;  // 2^-16

  const size_t xbase0 = (size_t)(node0 + 0 * 16 + lr) * 256 + lg * 8;
  const size_t xbase1 = (size_t)(node0 + 1 * 16 + lr) * 256 + lg * 8;

  fx4 acc2[4][2];
#pragma unroll
  for (int m = 0; m < 4; ++m)
#pragma unroll
    for (int n = 0; n < 2; ++n) acc2[m][n] = (fx4){0.f, 0.f, 0.f, 0.f};

  // X fragments for the current head: [ks*2+n]
  hf8 cxh[4], cxl[4];
#pragma unroll
  for (int ks = 0; ks < 2; ++ks) {
    cxh[ks * 2 + 0] = *(const hf8*)(aXhi + xbase0 + ks * 32);
    cxl[ks * 2 + 0] = *(const hf8*)(aXlo + xbase0 + ks * 32);
    cxh[ks * 2 + 1] = *(const hf8*)(aXhi + xbase1 + ks * 32);
    cxl[ks * 2 + 1] = *(const hf8*)(aXlo + xbase1 + ks * 32);
  }

#pragma unroll
  for (int h = 0; h < 4; ++h) {
    fx4 acc1[4][2];
#pragma unroll
    for (int m = 0; m < 4; ++m)
#pragma unroll
      for (int n = 0; n < 2; ++n) acc1[m][n] = (fx4){0.f, 0.f, 0.f, 0.f};

    // ---- GEMM1: acc1 = W1h^T @ X^T (last use of cx for this head) ----
#pragma unroll
    for (int ks = 0; ks < 2; ++ks) {
      const int ko = ks * 32 + lg * 8;
#pragma unroll
      for (int m = 0; m < 4; ++m) {
        size_t wo = (size_t)((h * 64 + m * 16 + lr) * 64 + ko);
        hf8 wah = *(const hf8*)(w1t_hi + wo);
        hf8 wal = *(const hf8*)(w1t_lo + wo);
#pragma unroll
        for (int n = 0; n < 2; ++n)
          acc1[m][n] = mfma3(acc1[m][n], wah, wal, cxh[ks * 2 + n], cxl[ks * 2 + n]);
      }
    }

    // reload cx for next head now; drains under epilogue + GEMM2
    if (h < 3) {
#pragma unroll
      for (int ks = 0; ks < 2; ++ks) {
        cxh[ks * 2 + 0] = *(const hf8*)(aXhi + xbase0 + (h + 1) * 64 + ks * 32);
        cxl[ks * 2 + 0] = *(const hf8*)(aXlo + xbase0 + (h + 1) * 64 + ks * 32);
        cxh[ks * 2 + 1] = *(const hf8*)(aXhi + xbase1 + (h + 1) * 64 + ks * 32);
        cxl[ks * 2 + 1] = *(const hf8*)(aXlo + xbase1 + (h + 1) * 64 + ks * 32);
      }
    }

    // ---- epilogue: scale, ELU, re-split, write t1 planes to LDS ----
#pragma unroll
    for (int m = 0; m < 4; ++m)
#pragma unroll
      for (int n = 0; n < 2; ++n) {
        hf4 hv, lv;
#pragma unroll
        for (int r = 0; r < 4; ++r) {
          float v = acc1[m][n][r] * DS;
          v = elu(v) * 256.f;
          _Float16 hi = (_Float16)v;
          hv[r] = hi;
          lv[r] = (_Float16)(v - (float)hi);
        }
        int nl = n * 16 + lr;
        int ro = (m * 32 + lg * 8) ^ ((nl & 7) << 4);
        *(hf4*)(myhi + nl * 128 + ro) = hv;
        *(hf4*)(mylo + nl * 128 + ro) = lv;
      }
    // per-wave LDS slice: same-wave DS FIFO orders write->read, no barrier

    // ---- GEMM2: acc2 += W2h^T @ t1^T ----
#pragma unroll
    for (int ks = 0; ks < 2; ++ks) {
      const int ko = ks * 32 + lg * 8;
      hf8 tbh[2], tbl[2];
#pragma unroll
      for (int n = 0; n < 2; ++n) {
        int nl = n * 16 + lr;
        int ro = (ks * 64 + lg * 16) ^ ((nl & 7) << 4);
        tbh[n] = *(const hf8*)(myhi + nl * 128 + ro);
        tbl[n] = *(const hf8*)(mylo + nl * 128 + ro);
      }
#pragma unroll
      for (int m = 0; m < 4; ++m) {
        size_t wo = (size_t)((h * 64 + m * 16 + lr) * 64 + ko);
        hf8 wah = *(const hf8*)(w2t_hi + wo);
        hf8 wal = *(const hf8*)(w2t_lo + wo);
#pragma unroll
        for (int n = 0; n < 2; ++n)
          acc2[m][n] = mfma3(acc2[m][n], wah, wal, tbh[n], tbl[n]);
      }
    }
  }

  // ---- h2 store + e2s/e2d dots ----
  float ps[2] = {0.f, 0.f};
  float pd[2] = {0.f, 0.f};
#pragma unroll
  for (int m = 0; m < 4; ++m) {
    fx4 al = *(const fx4*)(a2v + m * 16 + lg * 4);
    fx4 ar = *(const fx4*)(a2v + 64 + m * 16 + lg * 4);
#pragma unroll
    for (int n = 0; n < 2; ++n) {
      fx4 v = acc2[m][n] * DS;
      int node = node0 + n * 16 + lr;
      if (node < NUM_NODES)
        *(fx4*)(h2g + (size_t)node * 64 + m * 16 + lg * 4) = v;
      ps[n] += v[0] * al[0] + v[1] * al[1] + v[2] * al[2] + v[3] * al[3];
      pd[n] += v[0] * ar[0] + v[1] * ar[1] + v[2] * ar[2] + v[3] * ar[3];
    }
  }
#pragma unroll
  for (int n = 0; n < 2; ++n) {
    float s = ps[n], d = pd[n];
    s += __shfl_xor(s, 16, 64);
    s += __shfl_xor(s, 32, 64);
    d += __shfl_xor(d, 16, 64);
    d += __shfl_xor(d, 32, 64);
    int node = node0 + n * 16 + lr;
    if (lg == n && node < NUM_NODES) {
      e2s[node] = s;
      e2d[node] = d;
    }
  }
}

// ---------------- layer-2 aggregation + residual ----------------
__global__ __launch_bounds__(256) void agg2_kernel(
    const int* __restrict__ offsets, const int* __restrict__ srcs,
    const float* __restrict__ e2s, const float* __restrict__ e2d,
    const int* __restrict__ nodelist, const float* __restrict__ h2,
    const float* __restrict__ ut, const float* __restrict__ it,
    float* __restrict__ hfin) {
  int wid = threadIdx.x >> 6, lane = threadIdx.x & 63;
  int idx = blockIdx.x * 4 + wid;
  if (idx >= 2 * BATCH) return;
  int node = nodelist[idx];
  int beg = offsets[node], end = offsets[node + 1];
  int deg = end - beg;
  float edv = e2d[node];

  if (deg <= 64) {
    int s = 0;
    float w = 0.f;
    if (lane < deg) {
      s = srcs[beg + lane];
      w = lrexp(e2s[s] + edv);
    }
    w = wnorm(w);

    const int g = lane >> 4, fl = lane & 15;
    float4 acc = make_float4(0.f, 0.f, 0.f, 0.f);
#pragma unroll 4
    for (int e = 0; e < deg; e += 4) {
      int ei = e + g;
      int sg = __shfl(s, ei, 64);
      float wg = __shfl(w, ei, 64);
      float4 hv = *(const float4*)(h2 + (size_t)sg * 64 + fl * 4);
      acc.x += wg * hv.x; acc.y += wg * hv.y; acc.z += wg * hv.z; acc.w += wg * hv.w;
    }
    fold4(acc);
    if (g == 0) {
      const float* rp = (node < NUM_USERS) ? ut + (size_t)node * 64
                                           : it + (size_t)(node - NUM_USERS) * 64;
      float4 res = *(const float4*)(rp + fl * 4);
      acc.x += res.x; acc.y += res.y; acc.z += res.z; acc.w += res.w;
      *(float4*)(hfin + (size_t)node * 64 + fl * 4) = acc;
    }
  } else {
    float psum = 0.f;
    for (int e = beg + lane; e < end; e += 64) {
      int s = srcs[e];
      psum += lrexp(e2s[s] + edv);
    }
#pragma unroll
    for (int off = 32; off; off >>= 1) psum += __shfl_xor(psum, off, 64);
    float inv = 1.f / (psum + 1e-8f);
    float acc = 0.f;
    for (int e = beg; e < end; ++e) {
      int s0 = srcs[e];
      acc += lrexp(e2s[s0] + edv) * inv * h2[(size_t)s0 * 64 + lane];
    }
    float res = (node < NUM_USERS) ? ut[(size_t)node * 64 + lane]
                                   : it[(size_t)(node - NUM_USERS) * 64 + lane];
    hfin[(size_t)node * 64 + lane] = acc + res;
  }
}

// ---------------- final batched dot ----------------
__global__ __launch_bounds__(256) void final_kernel(
    const float* __restrict__ hf, const int* __restrict__ uid,
    const int* __restrict__ iid, float* __restrict__ out) {
  int wid = threadIdx.x >> 6, lane = threadIdx.x & 63;
  int idx = blockIdx.x * 4 + wid;
  if (idx >= BATCH) return;
  int u = uid[idx], v = iid[idx];
  float a = hf[(size_t)u * 64 + lane];
  float b = hf[(size_t)(NUM_USERS + v) * 64 + lane];
  float p = a * b;
#pragma unroll
  for (int off = 32; off; off >>= 1) p += __shfl_xor(p, off, 64);
  if (lane == 0) out[idx] = p;
}

extern "C" void kernel_launch(void* const* d_in, const int* in_sizes, int n_in,
                              void* d_out, int out_size, void* d_ws, size_t ws_size,
                              hipStream_t stream) {
  const float* user_table = (const float*)d_in[0];
  const float* item_table = (const float*)d_in[1];
  const float* W1 = (const float*)d_in[2];
  const float* a1 = (const float*)d_in[3];
  const float* W2 = (const float*)d_in[4];
  const float* a2 = (const float*)d_in[5];
  const int* edge_index = (const int*)d_in[6];
  const int* user_ids = (const int*)d_in[7];
  const int* item_ids = (const int*)d_in[8];
  float* out = (float*)d_out;

  const int* src = edge_index;
  const int* dst = edge_index + NUM_EDGES;

  // ---- workspace layout (elements) ----
  float* ws = (float*)d_ws;
  size_t off = 0;
  auto falloc = [&](size_t n) { float* p = ws + off; off += n; return p; };
  float* h2  = falloc((size_t)NUM_NODES * 64);
  float* e1s = falloc((size_t)NUM_NODES * 4);
  float* e1d = falloc((size_t)NUM_NODES * 4);
  float* e2s = falloc(NUM_NODES);
  float* e2d = falloc(NUM_NODES);
  float* w1a = falloc(256);
  float* w1b = falloc(256);
  int* offsets  = (int*)falloc(NUM_NODES + 1);
  int* srcs     = (int*)falloc(NUM_EDGES);
  int* nodelist = (int*)falloc(2 * BATCH);
  int* bcnt     = (int*)falloc(NBUCK);
  int* bbase    = (int*)falloc(NBUCK + 1);
  int* bcursor  = (int*)falloc(NBUCK);
  int* gcnt     = (int*)falloc(2);
  int* Ls       = (int*)falloc(NNPAD);
  int* Lm       = (int*)falloc(NNPAD);
  off = (off + 3) & ~(size_t)3;  // 16B-align the f16 planes
  _Float16* aggXhi = (_Float16*)(ws + off); off += (size_t)NNPAD * 128;
  _Float16* aggXlo = (_Float16*)(ws + off); off += (size_t)NNPAD * 128;

  // ebuf (16 MB) aliases plane head — dead before aggX writes (pad rows at +76.8MB safe).
  int2* ebuf = (int2*)aggXhi;
  // hfin aliases plane head — aggX planes dead after trans_mfma reads.
  float* hfin = (float*)aggXhi;
  // weight f16 planes: fresh allocation (128 KB), no lifetime conflicts
  _Float16* w1t_hi = (_Float16*)falloc(4 * 64 * 64 / 2 + 16);
  _Float16* w1t_lo = (_Float16*)falloc(4 * 64 * 64 / 2 + 16);
  _Float16* w2t_hi = (_Float16*)falloc(4 * 64 * 64 / 2 + 16);
  _Float16* w2t_lo = (_Float16*)falloc(4 * 64 * 64 / 2 + 16);

  flag_kernel<<<(BATCH + 255) / 256, 256, 0, stream>>>(user_ids, item_ids,
                                                       nodelist, bcnt, gcnt,
                                                       aggXhi, aggXlo);
  bhist_kernel<<<PA_BLOCKS, 256, 0, stream>>>(dst, bcnt);
  bscan_kernel<<<1, 1024, 0, stream>>>(bcnt, bbase, bcursor, offsets);
  bpart_kernel<<<PA_BLOCKS, 256, 0, stream>>>(src, dst, bcursor, ebuf);
  bcsr_kernel<<<NBUCK, 256, 0, stream>>>(ebuf, bbase, offsets, srcs,
                                         gcnt, Ls, Lm);

  prep_kernel<<<2, 256, 0, stream>>>(W1, a1, W2, w1a, w1b,
                                     w1t_hi, w1t_lo, w2t_hi, w2t_lo);
  e1g_kernel<<<(NNPAD + 15) / 16, 256, 0, stream>>>(user_table, item_table,
                                                    w1a, w1b, e1s, e1d);

  aggX_kernel<<<AGG_MBLK + AGG_SBLK, 256, 0, stream>>>(Ls, Lm, gcnt, offsets, srcs,
                                                       e1s, e1d, user_table,
                                                       item_table, aggXhi, aggXlo);
  trans_mfma_kernel<<<TBLK2, 256, 0, stream>>>(aggXhi, aggXlo,
                                               w1t_hi, w1t_lo, w2t_hi, w2t_lo,
                                               a2, h2, e2s, e2d);

  agg2_kernel<<<(2 * BATCH + 3) / 4, 256, 0, stream>>>(offsets, srcs, e2s, e2d,
                                                       nodelist, h2,
                                                       user_table, item_table, hfin);
  final_kernel<<<(BATCH + 3) / 4, 256, 0, stream>>>(hfin, user_ids, item_ids, out);
}

// Round 12
// 468.428 us; speedup vs baseline: 1.2119x; 1.0447x over previous
//
#include <hip/hip_runtime.h>
#include <cstdint>
#include <cstddef>

#define NUM_USERS 100000
#define NUM_ITEMS 50000
#define NUM_NODES 150000
#define NUM_EDGES 2000000
#define BATCH 16384
#define BSHIFT 8                                   // 256 nodes per bucket
#define NBUCK ((NUM_NODES + 255) >> BSHIFT)        // 586 buckets
#define PA_EDGES 8192                              // edges per block, bhist/bpart
#define PA_BLOCKS ((NUM_EDGES + PA_EDGES - 1) / PA_EDGES)  // 245
#define NNPAD 150016                               // NUM_NODES rounded to 128
#define TBLK2 (NNPAD / 128)                        // 1172 blocks (4 waves x 32 nodes)
#define AGG_MBLK ((NNPAD + 3) / 4)                 // mid-path blocks (1 node/wave)
#define AGG_SBLK ((NNPAD + 15) / 16)               // small-path blocks (4 nodes/wave)
#define E1_BLK ((NNPAD + 15) / 16)                 // e1 blocks (16 nodes/block)

typedef _Float16 hf8 __attribute__((ext_vector_type(8)));
typedef _Float16 hf4 __attribute__((ext_vector_type(4)));
typedef float fx4 __attribute__((ext_vector_type(4)));

// ---------------- setup: counters zero + aggX pad-row zero + prep (merged) -------------
// blocks 0..7: zero bcnt/gcnt + pad rows. blocks 8..9: prep (proj1 / weight planes).
// All workloads independent -> safe in one launch. bhist stays separate (needs zeroed
// bcnt COMPLETE before its atomics; no cross-block ordering within a launch).
__global__ void setup_kernel(const float* __restrict__ W1, const float* __restrict__ a1,
                             const float* __restrict__ W2,
                             int* __restrict__ bcnt, int* __restrict__ gcnt,
                             _Float16* __restrict__ aXhi, _Float16* __restrict__ aXlo,
                             float* __restrict__ w1a, float* __restrict__ w1b,
                             _Float16* __restrict__ w1t_hi, _Float16* __restrict__ w1t_lo,
                             _Float16* __restrict__ w2t_hi, _Float16* __restrict__ w2t_lo) {
  int t = threadIdx.x;
  if (blockIdx.x < 8) {
    int i = blockIdx.x * 256 + t;
    if (i < NBUCK) bcnt[i] = 0;
    if (i < 2) gcnt[i] = 0;
    if (i < 2048) {  // 16 pad rows x 256 halves = 2048 floats per plane
      ((float*)(aXhi + (size_t)NUM_NODES * 256))[i] = 0.f;
      ((float*)(aXlo + (size_t)NUM_NODES * 256))[i] = 0.f;
    }
    return;
  }
  int h = t >> 6;
  if (blockIdx.x == 8) {
    int k = t & 63;
    float sa = 0.f, sb = 0.f;
    for (int f = 0; f < 64; ++f) {
      float w = W1[(size_t)k * 256 + h * 64 + f];
      sa += w * a1[h * 128 + f];
      sb += w * a1[h * 128 + 64 + f];
    }
    w1a[h * 64 + k] = sa;
    w1b[h * 64 + k] = sb;
  } else {
    int a = t & 63;
    for (int k = 0; k < 64; ++k) {
      float w = W1[(size_t)k * 256 + h * 64 + a] * 256.f;
      _Float16 hi = (_Float16)w;
      w1t_hi[(size_t)(h * 64 + a) * 64 + k] = hi;
      w1t_lo[(size_t)(h * 64 + a) * 64 + k] = (_Float16)(w - (float)hi);
      float v = W2[(size_t)(h * 64 + k) * 64 + a] * 256.f;
      _Float16 hi2 = (_Float16)v;
      w2t_hi[(size_t)(h * 64 + a) * 64 + k] = hi2;
      w2t_lo[(size_t)(h * 64 + a) * 64 + k] = (_Float16)(v - (float)hi2);
    }
  }
}

// ---------------- bucketed CSR construction ----------------
__global__ __launch_bounds__(256) void bhist_kernel(const int* __restrict__ dst,
                                                    int* __restrict__ bcnt) {
  __shared__ int bh[NBUCK];
  int t = threadIdx.x;
  for (int u = t; u < NBUCK; u += 256) bh[u] = 0;
  __syncthreads();
  int base = blockIdx.x * PA_EDGES;
#pragma unroll
  for (int u = 0; u < PA_EDGES / 256; ++u) {
    int e = base + u * 256 + t;
    if (e < NUM_EDGES) atomicAdd(&bh[dst[e] >> BSHIFT], 1);
  }
  __syncthreads();
  for (int u = t; u < NBUCK; u += 256) {
    int v = bh[u];
    if (v) atomicAdd(&bcnt[u], v);
  }
}

__global__ void bscan_kernel(const int* __restrict__ bcnt, int* __restrict__ bbase,
                             int* __restrict__ bcursor, int* __restrict__ offsets) {
  __shared__ int sh[1024];
  int t = threadIdx.x;
  int v = (t < NBUCK) ? bcnt[t] : 0;
  sh[t] = v;
  __syncthreads();
  for (int off = 1; off < 1024; off <<= 1) {
    int x = (t >= off) ? sh[t - off] : 0;
    __syncthreads();
    sh[t] += x;
    __syncthreads();
  }
  if (t < NBUCK) {
    bbase[t] = sh[t] - v;
    bcursor[t] = sh[t] - v;
  }
  if (t == NBUCK - 1) {
    bbase[NBUCK] = sh[t];
    offsets[NUM_NODES] = sh[t];  // == NUM_EDGES
  }
}

__global__ __launch_bounds__(256) void bpart_kernel(const int* __restrict__ src,
                                                    const int* __restrict__ dst,
                                                    int* __restrict__ bcursor,
                                                    int2* __restrict__ ebuf) {
  __shared__ int lcnt[NBUCK];
  __shared__ int lbase[NBUCK];
  int t = threadIdx.x;
  for (int u = t; u < NBUCK; u += 256) lcnt[u] = 0;
  __syncthreads();
  int base = blockIdx.x * PA_EDGES;
#pragma unroll
  for (int u = 0; u < PA_EDGES / 256; ++u) {
    int e = base + u * 256 + t;
    if (e < NUM_EDGES) atomicAdd(&lcnt[dst[e] >> BSHIFT], 1);
  }
  __syncthreads();
  for (int u = t; u < NBUCK; u += 256) {
    int v = lcnt[u];
    lbase[u] = v ? atomicAdd(&bcursor[u], v) : 0;
    lcnt[u] = 0;
  }
  __syncthreads();
#pragma unroll
  for (int u = 0; u < PA_EDGES / 256; ++u) {
    int e = base + u * 256 + t;
    if (e < NUM_EDGES) {
      int d = dst[e];
      int b = d >> BSHIFT;
      int p = lbase[b] + atomicAdd(&lcnt[b], 1);
      ebuf[p] = make_int2(src[e], d);
    }
  }
}

__device__ __forceinline__ const float* row_ptr(int s, const float* __restrict__ ut,
                                                const float* __restrict__ it) {
  return (s < NUM_USERS) ? ut + (size_t)s * 64 : it + (size_t)(s - NUM_USERS) * 64;
}

// bcsr (+deg classification) with e1g appended as extra blocks (independent workloads)
__global__ __launch_bounds__(256) void bcsr_e1_kernel(
    const int2* __restrict__ ebuf, const int* __restrict__ bbase,
    int* __restrict__ offsets, int* __restrict__ srcs,
    int* __restrict__ gcnt, int* __restrict__ Ls, int* __restrict__ Lm,
    const float* __restrict__ ut, const float* __restrict__ it,
    const float* __restrict__ w1a, const float* __restrict__ w1b,
    float* __restrict__ e1s, float* __restrict__ e1d) {
  __shared__ int ncnt[256];
  __shared__ int sh[256];
  __shared__ int lcur[256];
  __shared__ int c0, c1, b0, b1;
  int t = threadIdx.x;

  if (blockIdx.x >= NBUCK) {
    // ---------- e1 tables: 4 nodes per wave, 16 lanes per node ----------
    int wave = t >> 6, lane = t & 63;
    int g = lane >> 4, fl = lane & 15;
    int node = (blockIdx.x - NBUCK) * 16 + wave * 4 + g;
    bool valid = node < NUM_NODES;
    float4 xv = make_float4(0.f, 0.f, 0.f, 0.f);
    if (valid) xv = *(const float4*)(row_ptr(node, ut, it) + fl * 4);
    float ps[4], pd[4];
#pragma unroll
    for (int h = 0; h < 4; ++h) {
      float4 wa = *(const float4*)(w1a + h * 64 + fl * 4);
      float4 wb = *(const float4*)(w1b + h * 64 + fl * 4);
      ps[h] = xv.x * wa.x + xv.y * wa.y + xv.z * wa.z + xv.w * wa.w;
      pd[h] = xv.x * wb.x + xv.y * wb.y + xv.z * wb.z + xv.w * wb.w;
    }
#pragma unroll
    for (int off = 8; off; off >>= 1) {
#pragma unroll
      for (int h = 0; h < 4; ++h) {
        ps[h] += __shfl_xor(ps[h], off, 16);
        pd[h] += __shfl_xor(pd[h], off, 16);
      }
    }
    if (valid && fl == 0) {
      *(float4*)(e1s + (size_t)node * 4) = make_float4(ps[0], ps[1], ps[2], ps[3]);
      *(float4*)(e1d + (size_t)node * 4) = make_float4(pd[0], pd[1], pd[2], pd[3]);
    }
    return;
  }

  // ---------- bcsr ----------
  int b = blockIdx.x;
  int node0 = b << BSHIFT;
  int ebeg = bbase[b], eend = bbase[b + 1];
  ncnt[t] = 0;
  if (t == 0) { c0 = 0; c1 = 0; }
  __syncthreads();
  for (int i = ebeg + t; i < eend; i += 256)
    atomicAdd(&ncnt[ebuf[i].y - node0], 1);
  __syncthreads();
  int v = ncnt[t];
  sh[t] = v;
  __syncthreads();
  for (int off = 1; off < 256; off <<= 1) {
    int x = (t >= off) ? sh[t - off] : 0;
    __syncthreads();
    sh[t] += x;
    __syncthreads();
  }
  int excl = ebeg + sh[t] - v;
  if (node0 + t < NUM_NODES) offsets[node0 + t] = excl;
  lcur[t] = excl;
  int cls = -1, rank = 0;
  if (node0 + t < NUM_NODES) {
    cls = (v <= 16) ? 0 : 1;
    rank = atomicAdd(cls == 0 ? &c0 : &c1, 1);
  }
  __syncthreads();
  if (t == 0) {
    b0 = atomicAdd(&gcnt[0], c0);
    b1 = atomicAdd(&gcnt[1], c1);
  }
  __syncthreads();
  if (cls == 0) Ls[b0 + rank] = node0 + t;
  else if (cls == 1) Lm[b1 + rank] = node0 + t;
  for (int i = ebeg + t; i < eend; i += 256) {
    int2 ed = ebuf[i];
    int p = atomicAdd(&lcur[ed.y - node0], 1);
    srcs[p] = ed.x;
  }
}

__device__ __forceinline__ float lrexp(float x) {
  x = x > 0.f ? x : 0.2f * x;
  return __expf(x);
}

__device__ __forceinline__ float wnorm(float w) {
  float sum = w;
#pragma unroll
  for (int off = 32; off; off >>= 1) sum += __shfl_xor(sum, off, 64);
  return w * (1.f / (sum + 1e-8f));
}

__device__ __forceinline__ void fold4(float4& a) {
#pragma unroll
  for (int off = 16; off <= 32; off <<= 1) {
    a.x += __shfl_xor(a.x, off, 64);
    a.y += __shfl_xor(a.y, off, 64);
    a.z += __shfl_xor(a.z, off, 64);
    a.w += __shfl_xor(a.w, off, 64);
  }
}

__device__ __forceinline__ float elu(float x) {
  return x > 0.f ? x : (__expf(x) - 1.f);
}

// split x*256 into f16 hi + f16 lo (exact pow2 scale keeps lo out of denormals)
__device__ __forceinline__ void split4(float4 o, hf4& hv, hf4& lv) {
  float a0 = o.x * 256.f, a1 = o.y * 256.f, a2 = o.z * 256.f, a3 = o.w * 256.f;
  _Float16 h0 = (_Float16)a0, h1 = (_Float16)a1;
  _Float16 h2 = (_Float16)a2, h3 = (_Float16)a3;
  hv[0] = h0; hv[1] = h1; hv[2] = h2; hv[3] = h3;
  lv[0] = (_Float16)(a0 - (float)h0);
  lv[1] = (_Float16)(a1 - (float)h1);
  lv[2] = (_Float16)(a2 - (float)h2);
  lv[3] = (_Float16)(a3 - (float)h3);
}

__device__ __forceinline__ void splitstore(_Float16* __restrict__ hi,
                                           _Float16* __restrict__ lo,
                                           size_t idx, float v) {
  v *= 256.f;
  _Float16 h = (_Float16)v;
  hi[idx] = h;
  lo[idx] = (_Float16)(v - (float)h);
}

// ---------------- merged aggregation (verified R11 body, unchanged) ----------------
__global__ __launch_bounds__(256) void aggX_kernel(
    const int* __restrict__ Ls, const int* __restrict__ Lm,
    const int* __restrict__ gcnt,
    const int* __restrict__ offsets, const int* __restrict__ srcs,
    const float* __restrict__ e1s, const float* __restrict__ e1d,
    const float* __restrict__ ut, const float* __restrict__ it,
    _Float16* __restrict__ aXhi, _Float16* __restrict__ aXlo) {
  __shared__ int sS[4][68];                       // [wave][g*17 + e] (small path)
  __shared__ __align__(16) float4 sW[4][68];
  const int t = threadIdx.x;
  const int wave = t >> 6, lane = t & 63;
  const int g = lane >> 4, fl = lane & 15;

  if (blockIdx.x < AGG_MBLK) {
    // ---------- mid/big path (deg>16): 1 node/wave ----------
    int idx = blockIdx.x * 4 + wave;
    if (idx >= gcnt[1]) return;
    int node = Lm[idx];
    int beg = offsets[node], end = offsets[node + 1];
    int deg = end - beg;

    float edv0 = e1d[(size_t)node * 4 + 0];
    float edv1 = e1d[(size_t)node * 4 + 1];
    float edv2 = e1d[(size_t)node * 4 + 2];
    float edv3 = e1d[(size_t)node * 4 + 3];

    if (deg <= 64) {
      int s = 0;
      float w0 = 0.f, w1 = 0.f, w2 = 0.f, w3 = 0.f;
      if (lane < deg) {
        s = srcs[beg + lane];
        float4 ev = *(const float4*)(e1s + (size_t)s * 4);
        w0 = lrexp(ev.x + edv0);
        w1 = lrexp(ev.y + edv1);
        w2 = lrexp(ev.z + edv2);
        w3 = lrexp(ev.w + edv3);
      }
      w0 = wnorm(w0);
      w1 = wnorm(w1);
      w2 = wnorm(w2);
      w3 = wnorm(w3);

      float4 acc0 = make_float4(0.f, 0.f, 0.f, 0.f);
      float4 acc1 = acc0, acc2 = acc0, acc3 = acc0;
      for (int ebase = 0; ebase < deg; ebase += 16) {
        int i0 = ebase + g, i1 = ebase + 4 + g, i2 = ebase + 8 + g, i3 = ebase + 12 + g;
        int s0 = __shfl(s, i0, 64), s1 = __shfl(s, i1, 64);
        int s2 = __shfl(s, i2, 64), s3 = __shfl(s, i3, 64);
        float4 x0 = *(const float4*)(row_ptr(s0, ut, it) + fl * 4);
        float4 x1 = *(const float4*)(row_ptr(s1, ut, it) + fl * 4);
        float4 x2 = *(const float4*)(row_ptr(s2, ut, it) + fl * 4);
        float4 x3 = *(const float4*)(row_ptr(s3, ut, it) + fl * 4);
#pragma unroll
        for (int j = 0; j < 4; ++j) {
          int ei = ebase + j * 4 + g;
          float4 xv = (j == 0) ? x0 : (j == 1) ? x1 : (j == 2) ? x2 : x3;
          float wg0 = __shfl(w0, ei, 64);
          acc0.x += wg0 * xv.x; acc0.y += wg0 * xv.y;
          acc0.z += wg0 * xv.z; acc0.w += wg0 * xv.w;
          float wg1 = __shfl(w1, ei, 64);
          acc1.x += wg1 * xv.x; acc1.y += wg1 * xv.y;
          acc1.z += wg1 * xv.z; acc1.w += wg1 * xv.w;
          float wg2 = __shfl(w2, ei, 64);
          acc2.x += wg2 * xv.x; acc2.y += wg2 * xv.y;
          acc2.z += wg2 * xv.z; acc2.w += wg2 * xv.w;
          float wg3 = __shfl(w3, ei, 64);
          acc3.x += wg3 * xv.x; acc3.y += wg3 * xv.y;
          acc3.z += wg3 * xv.z; acc3.w += wg3 * xv.w;
        }
      }
      fold4(acc0); fold4(acc1); fold4(acc2); fold4(acc3);

      float4 o = (g == 0) ? acc0 : (g == 1) ? acc1 : (g == 2) ? acc2 : acc3;
      hf4 hv, lv;
      split4(o, hv, lv);
      *(hf4*)(aXhi + (size_t)node * 256 + lane * 4) = hv;
      *(hf4*)(aXlo + (size_t)node * 256 + lane * 4) = lv;
    } else {
      // generic fallback (deg > 64): lane = feature
      float s0 = 0.f, s1 = 0.f, s2 = 0.f, s3 = 0.f;
      for (int e = beg + lane; e < end; e += 64) {
        int s = srcs[e];
        float4 ev = *(const float4*)(e1s + (size_t)s * 4);
        s0 += lrexp(ev.x + edv0); s1 += lrexp(ev.y + edv1);
        s2 += lrexp(ev.z + edv2); s3 += lrexp(ev.w + edv3);
      }
#pragma unroll
      for (int off = 32; off; off >>= 1) {
        s0 += __shfl_xor(s0, off, 64);
        s1 += __shfl_xor(s1, off, 64);
        s2 += __shfl_xor(s2, off, 64);
        s3 += __shfl_xor(s3, off, 64);
      }
      float i0 = 1.f / (s0 + 1e-8f), i1 = 1.f / (s1 + 1e-8f);
      float i2 = 1.f / (s2 + 1e-8f), i3 = 1.f / (s3 + 1e-8f);
      float a0 = 0.f, a1 = 0.f, a2 = 0.f, a3 = 0.f;
      for (int e = beg; e < end; ++e) {
        int sn = srcs[e];
        float xv = row_ptr(sn, ut, it)[lane];
        float4 ev = *(const float4*)(e1s + (size_t)sn * 4);
        a0 += lrexp(ev.x + edv0) * i0 * xv;
        a1 += lrexp(ev.y + edv1) * i1 * xv;
        a2 += lrexp(ev.z + edv2) * i2 * xv;
        a3 += lrexp(ev.w + edv3) * i3 * xv;
      }
      splitstore(aXhi, aXlo, (size_t)node * 256 + 0 * 64 + lane, a0);
      splitstore(aXhi, aXlo, (size_t)node * 256 + 1 * 64 + lane, a1);
      splitstore(aXhi, aXlo, (size_t)node * 256 + 2 * 64 + lane, a2);
      splitstore(aXhi, aXlo, (size_t)node * 256 + 3 * 64 + lane, a3);
    }
    return;
  }

  // ---------- small path (deg<=16): 4 nodes/wave, 16 lanes/node ----------
  const int cnt = gcnt[0];
  const int widx = (blockIdx.x - AGG_MBLK) * 16 + wave * 4 + g;
  const int node = (widx < cnt) ? Ls[widx] : -1;

  int beg = 0, deg = 0;
  float4 ed = make_float4(0.f, 0.f, 0.f, 0.f);
  if (node >= 0) {
    beg = offsets[node];
    deg = offsets[node + 1] - beg;
    ed = *(const float4*)(e1d + (size_t)node * 4);   // broadcast within group
  }
  int s = 0;
  float w0 = 0.f, w1 = 0.f, w2 = 0.f, w3 = 0.f;
  if (fl < deg) {
    s = srcs[beg + fl];
    float4 ev = *(const float4*)(e1s + (size_t)s * 4);
    w0 = lrexp(ev.x + ed.x);
    w1 = lrexp(ev.y + ed.y);
    w2 = lrexp(ev.z + ed.z);
    w3 = lrexp(ev.w + ed.w);
  }
  float t0 = w0, t1 = w1, t2 = w2, t3 = w3;
#pragma unroll
  for (int off = 8; off; off >>= 1) {
    t0 += __shfl_xor(t0, off, 16);
    t1 += __shfl_xor(t1, off, 16);
    t2 += __shfl_xor(t2, off, 16);
    t3 += __shfl_xor(t3, off, 16);
  }
  w0 *= 1.f / (t0 + 1e-8f);
  w1 *= 1.f / (t1 + 1e-8f);
  w2 *= 1.f / (t2 + 1e-8f);
  w3 *= 1.f / (t3 + 1e-8f);
  sS[wave][g * 17 + fl] = s;
  sW[wave][g * 17 + fl] = make_float4(w0, w1, w2, w3);
  // no barrier needed: same-wave LDS write->read ordered by lgkmcnt

  float4 xr[16];
#pragma unroll
  for (int e = 0; e < 16; ++e) {
    int se = sS[wave][g * 17 + e];                 // broadcast read
    xr[e] = *(const float4*)(row_ptr(se, ut, it) + fl * 4);
  }

  float4 a0 = make_float4(0.f, 0.f, 0.f, 0.f);
  float4 a1 = a0, a2 = a0, a3 = a0;
#pragma unroll
  for (int e = 0; e < 16; ++e) {
    float4 w4 = sW[wave][g * 17 + e];
    float4 xv = xr[e];
    a0.x += w4.x * xv.x; a0.y += w4.x * xv.y; a0.z += w4.x * xv.z; a0.w += w4.x * xv.w;
    a1.x += w4.y * xv.x; a1.y += w4.y * xv.y; a1.z += w4.y * xv.z; a1.w += w4.y * xv.w;
    a2.x += w4.z * xv.x; a2.y += w4.z * xv.y; a2.z += w4.z * xv.z; a2.w += w4.z * xv.w;
    a3.x += w4.w * xv.x; a3.y += w4.w * xv.y; a3.z += w4.w * xv.z; a3.w += w4.w * xv.w;
  }
  if (node >= 0) {
    hf4 hv, lv;
    split4(a0, hv, lv);
    *(hf4*)(aXhi + (size_t)node * 256 + 0 * 64 + fl * 4) = hv;
    *(hf4*)(aXlo + (size_t)node * 256 + 0 * 64 + fl * 4) = lv;
    split4(a1, hv, lv);
    *(hf4*)(aXhi + (size_t)node * 256 + 1 * 64 + fl * 4) = hv;
    *(hf4*)(aXlo + (size_t)node * 256 + 1 * 64 + fl * 4) = lv;
    split4(a2, hv, lv);
    *(hf4*)(aXhi + (size_t)node * 256 + 2 * 64 + fl * 4) = hv;
    *(hf4*)(aXlo + (size_t)node * 256 + 2 * 64 + fl * 4) = lv;
    split4(a3, hv, lv);
    *(hf4*)(aXhi + (size_t)node * 256 + 3 * 64 + fl * 4) = hv;
    *(hf4*)(aXlo + (size_t)node * 256 + 3 * 64 + fl * 4) = lv;
  }
}

__device__ __forceinline__ fx4 mfma3(fx4 c, hf8 ah, hf8 al, hf8 bh, hf8 bl) {
  c = __builtin_amdgcn_mfma_f32_16x16x32_f16(ah, bh, c, 0, 0, 0);
  c = __builtin_amdgcn_mfma_f32_16x16x32_f16(al, bh, c, 0, 0, 0);
  c = __builtin_amdgcn_mfma_f32_16x16x32_f16(ah, bl, c, 0, 0, 0);
  return c;
}

// ---------------- dense transform on the MATRIX pipe (verified R8 version) ----------
__global__ __launch_bounds__(256, 2) void trans_mfma_kernel(
    const _Float16* __restrict__ aXhi, const _Float16* __restrict__ aXlo,
    const _Float16* __restrict__ w1t_hi, const _Float16* __restrict__ w1t_lo,
    const _Float16* __restrict__ w2t_hi, const _Float16* __restrict__ w2t_lo,
    const float* __restrict__ a2v,
    float* __restrict__ h2g, float* __restrict__ e2s, float* __restrict__ e2d) {
  __shared__ __align__(16) _Float16 t1hi[4][32 * 64];
  __shared__ __align__(16) _Float16 t1lo[4][32 * 64];
  const int wave = threadIdx.x >> 6;
  const int l = threadIdx.x & 63;
  const int lr = l & 15, lg = l >> 4;
  const int node0 = (blockIdx.x * 4 + wave) * 32;
  char* myhi = (char*)&t1hi[wave][0];
  char* mylo = (char*)&t1lo[wave][0];
  const float DS = 1.52587890625e-05f;  // 2^-16

  const size_t xbase0 = (size_t)(node0 + 0 * 16 + lr) * 256 + lg * 8;
  const size_t xbase1 = (size_t)(node0 + 1 * 16 + lr) * 256 + lg * 8;

  fx4 acc2[4][2];
#pragma unroll
  for (int m = 0; m < 4; ++m)
#pragma unroll
    for (int n = 0; n < 2; ++n) acc2[m][n] = (fx4){0.f, 0.f, 0.f, 0.f};

  // X fragments for the current head: [ks*2+n]
  hf8 cxh[4], cxl[4];
#pragma unroll
  for (int ks = 0; ks < 2; ++ks) {
    cxh[ks * 2 + 0] = *(const hf8*)(aXhi + xbase0 + ks * 32);
    cxl[ks * 2 + 0] = *(const hf8*)(aXlo + xbase0 + ks * 32);
    cxh[ks * 2 + 1] = *(const hf8*)(aXhi + xbase1 + ks * 32);
    cxl[ks * 2 + 1] = *(const hf8*)(aXlo + xbase1 + ks * 32);
  }

#pragma unroll
  for (int h = 0; h < 4; ++h) {
    fx4 acc1[4][2];
#pragma unroll
    for (int m = 0; m < 4; ++m)
#pragma unroll
      for (int n = 0; n < 2; ++n) acc1[m][n] = (fx4){0.f, 0.f, 0.f, 0.f};

    // ---- GEMM1: acc1 = W1h^T @ X^T (last use of cx for this head) ----
#pragma unroll
    for (int ks = 0; ks < 2; ++ks) {
      const int ko = ks * 32 + lg * 8;
#pragma unroll
      for (int m = 0; m < 4; ++m) {
        size_t wo = (size_t)((h * 64 + m * 16 + lr) * 64 + ko);
        hf8 wah = *(const hf8*)(w1t_hi + wo);
        hf8 wal = *(const hf8*)(w1t_lo + wo);
#pragma unroll
        for (int n = 0; n < 2; ++n)
          acc1[m][n] = mfma3(acc1[m][n], wah, wal, cxh[ks * 2 + n], cxl[ks * 2 + n]);
      }
    }

    // reload cx for next head now; drains under epilogue + GEMM2
    if (h < 3) {
#pragma unroll
      for (int ks = 0; ks < 2; ++ks) {
        cxh[ks * 2 + 0] = *(const hf8*)(aXhi + xbase0 + (h + 1) * 64 + ks * 32);
        cxl[ks * 2 + 0] = *(const hf8*)(aXlo + xbase0 + (h + 1) * 64 + ks * 32);
        cxh[ks * 2 + 1] = *(const hf8*)(aXhi + xbase1 + (h + 1) * 64 + ks * 32);
        cxl[ks * 2 + 1] = *(const hf8*)(aXlo + xbase1 + (h + 1) * 64 + ks * 32);
      }
    }

    // ---- epilogue: scale, ELU, re-split, write t1 planes to LDS ----
#pragma unroll
    for (int m = 0; m < 4; ++m)
#pragma unroll
      for (int n = 0; n < 2; ++n) {
        hf4 hv, lv;
#pragma unroll
        for (int r = 0; r < 4; ++r) {
          float v = acc1[m][n][r] * DS;
          v = elu(v) * 256.f;
          _Float16 hi = (_Float16)v;
          hv[r] = hi;
          lv[r] = (_Float16)(v - (float)hi);
        }
        int nl = n * 16 + lr;
        int ro = (m * 32 + lg * 8) ^ ((nl & 7) << 4);
        *(hf4*)(myhi + nl * 128 + ro) = hv;
        *(hf4*)(mylo + nl * 128 + ro) = lv;
      }
    // per-wave LDS slice: same-wave DS FIFO orders write->read, no barrier

    // ---- GEMM2: acc2 += W2h^T @ t1^T ----
#pragma unroll
    for (int ks = 0; ks < 2; ++ks) {
      const int ko = ks * 32 + lg * 8;
      hf8 tbh[2], tbl[2];
#pragma unroll
      for (int n = 0; n < 2; ++n) {
        int nl = n * 16 + lr;
        int ro = (ks * 64 + lg * 16) ^ ((nl & 7) << 4);
        tbh[n] = *(const hf8*)(myhi + nl * 128 + ro);
        tbl[n] = *(const hf8*)(mylo + nl * 128 + ro);
      }
#pragma unroll
      for (int m = 0; m < 4; ++m) {
        size_t wo = (size_t)((h * 64 + m * 16 + lr) * 64 + ko);
        hf8 wah = *(const hf8*)(w2t_hi + wo);
        hf8 wal = *(const hf8*)(w2t_lo + wo);
#pragma unroll
        for (int n = 0; n < 2; ++n)
          acc2[m][n] = mfma3(acc2[m][n], wah, wal, tbh[n], tbl[n]);
      }
    }
  }

  // ---- h2 store + e2s/e2d dots ----
  float ps[2] = {0.f, 0.f};
  float pd[2] = {0.f, 0.f};
#pragma unroll
  for (int m = 0; m < 4; ++m) {
    fx4 al = *(const fx4*)(a2v + m * 16 + lg * 4);
    fx4 ar = *(const fx4*)(a2v + 64 + m * 16 + lg * 4);
#pragma unroll
    for (int n = 0; n < 2; ++n) {
      fx4 v = acc2[m][n] * DS;
      int node = node0 + n * 16 + lr;
      if (node < NUM_NODES)
        *(fx4*)(h2g + (size_t)node * 64 + m * 16 + lg * 4) = v;
      ps[n] += v[0] * al[0] + v[1] * al[1] + v[2] * al[2] + v[3] * al[3];
      pd[n] += v[0] * ar[0] + v[1] * ar[1] + v[2] * ar[2] + v[3] * ar[3];
    }
  }
#pragma unroll
  for (int n = 0; n < 2; ++n) {
    float s = ps[n], d = pd[n];
    s += __shfl_xor(s, 16, 64);
    s += __shfl_xor(s, 32, 64);
    d += __shfl_xor(d, 16, 64);
    d += __shfl_xor(d, 32, 64);
    int node = node0 + n * 16 + lr;
    if (lg == n && node < NUM_NODES) {
      e2s[node] = s;
      e2d[node] = d;
    }
  }
}

// ---------------- layer-2 aggregation of one node into registers --------------------
// Returns the final (aggregated + residual) row as a float4 per lane at feature
// offset fl*4, replicated across all four 16-lane groups.
__device__ __forceinline__ float4 agg2_node(
    int node, const int* __restrict__ offsets, const int* __restrict__ srcs,
    const float* __restrict__ e2s, const float* __restrict__ e2d,
    const float* __restrict__ h2, const float* __restrict__ ut,
    const float* __restrict__ it, int lane, int g, int fl) {
  int beg = offsets[node], end = offsets[node + 1];
  int deg = end - beg;
  float edv = e2d[node];
  const float* rp = (node < NUM_USERS) ? ut + (size_t)node * 64
                                       : it + (size_t)(node - NUM_USERS) * 64;

  if (deg <= 64) {
    int s = 0;
    float w = 0.f;
    if (lane < deg) {
      s = srcs[beg + lane];
      w = lrexp(e2s[s] + edv);
    }
    w = wnorm(w);
    float4 acc = make_float4(0.f, 0.f, 0.f, 0.f);
#pragma unroll 4
    for (int e = 0; e < deg; e += 4) {
      int ei = e + g;
      int sg = __shfl(s, ei, 64);
      float wg = __shfl(w, ei, 64);
      float4 hv = *(const float4*)(h2 + (size_t)sg * 64 + fl * 4);
      acc.x += wg * hv.x; acc.y += wg * hv.y; acc.z += wg * hv.z; acc.w += wg * hv.w;
    }
    fold4(acc);  // all 4 groups now hold the group-summed row per fl
    float4 res = *(const float4*)(rp + fl * 4);
    acc.x += res.x; acc.y += res.y; acc.z += res.z; acc.w += res.w;
    return acc;
  } else {
    float psum = 0.f;
    for (int e = beg + lane; e < end; e += 64) {
      int s = srcs[e];
      psum += lrexp(e2s[s] + edv);
    }
#pragma unroll
    for (int off = 32; off; off >>= 1) psum += __shfl_xor(psum, off, 64);
    float inv = 1.f / (psum + 1e-8f);
    float acc = 0.f;
    for (int e = beg; e < end; ++e) {
      int s0 = srcs[e];
      acc += lrexp(e2s[s0] + edv) * inv * h2[(size_t)s0 * 64 + lane];
    }
    acc += rp[lane];  // residual, feature = lane
    // pack lane-scalar layout to per-fl float4 (replicated across groups)
    float4 r;
    r.x = __shfl(acc, fl * 4 + 0, 64);
    r.y = __shfl(acc, fl * 4 + 1, 64);
    r.z = __shfl(acc, fl * 4 + 2, 64);
    r.w = __shfl(acc, fl * 4 + 3, 64);
    return r;
  }
}

// ---------------- fused layer-2 aggregation + final dot (one wave per batch pair) ----
__global__ __launch_bounds__(256) void agg2f_kernel(
    const int* __restrict__ offsets, const int* __restrict__ srcs,
    const float* __restrict__ e2s, const float* __restrict__ e2d,
    const int* __restrict__ uid, const int* __restrict__ iid,
    const float* __restrict__ h2, const float* __restrict__ ut,
    const float* __restrict__ it, float* __restrict__ out) {
  int wid = threadIdx.x >> 6, lane = threadIdx.x & 63;
  int idx = blockIdx.x * 4 + wid;
  if (idx >= BATCH) return;
  const int g = lane >> 4, fl = lane & 15;
  int u = uid[idx];
  int v = NUM_USERS + iid[idx];
  float4 ru = agg2_node(u, offsets, srcs, e2s, e2d, h2, ut, it, lane, g, fl);
  float4 rv = agg2_node(v, offsets, srcs, e2s, e2d, h2, ut, it, lane, g, fl);
  float pr = ru.x * rv.x + ru.y * rv.y + ru.z * rv.z + ru.w * rv.w;
#pragma unroll
  for (int off = 8; off; off >>= 1) pr += __shfl_xor(pr, off, 16);
  if (lane == 0) out[idx] = pr;
}

extern "C" void kernel_launch(void* const* d_in, const int* in_sizes, int n_in,
                              void* d_out, int out_size, void* d_ws, size_t ws_size,
                              hipStream_t stream) {
  const float* user_table = (const float*)d_in[0];
  const float* item_table = (const float*)d_in[1];
  const float* W1 = (const float*)d_in[2];
  const float* a1 = (const float*)d_in[3];
  const float* W2 = (const float*)d_in[4];
  const float* a2 = (const float*)d_in[5];
  const int* edge_index = (const int*)d_in[6];
  const int* user_ids = (const int*)d_in[7];
  const int* item_ids = (const int*)d_in[8];
  float* out = (float*)d_out;

  const int* src = edge_index;
  const int* dst = edge_index + NUM_EDGES;

  // ---- workspace layout (elements) ----
  float* ws = (float*)d_ws;
  size_t off = 0;
  auto falloc = [&](size_t n) { float* p = ws + off; off += n; return p; };
  float* h2  = falloc((size_t)NUM_NODES * 64);
  float* e1s = falloc((size_t)NUM_NODES * 4);
  float* e1d = falloc((size_t)NUM_NODES * 4);
  float* e2s = falloc(NUM_NODES);
  float* e2d = falloc(NUM_NODES);
  float* w1a = falloc(256);
  float* w1b = falloc(256);
  int* offsets  = (int*)falloc(NUM_NODES + 1);
  int* srcs     = (int*)falloc(NUM_EDGES);
  int* bcnt     = (int*)falloc(NBUCK);
  int* bbase    = (int*)falloc(NBUCK + 1);
  int* bcursor  = (int*)falloc(NBUCK);
  int* gcnt     = (int*)falloc(2);
  int* Ls       = (int*)falloc(NNPAD);
  int* Lm       = (int*)falloc(NNPAD);
  off = (off + 3) & ~(size_t)3;  // 16B-align the f16 planes
  _Float16* aggXhi = (_Float16*)(ws + off); off += (size_t)NNPAD * 128;
  _Float16* aggXlo = (_Float16*)(ws + off); off += (size_t)NNPAD * 128;

  // ebuf (16 MB) aliases plane head — dead before aggX writes (pad rows at +76.8MB safe).
  int2* ebuf = (int2*)aggXhi;
  // weight f16 planes: fresh allocation (128 KB), no lifetime conflicts
  _Float16* w1t_hi = (_Float16*)falloc(4 * 64 * 64 / 2 + 16);
  _Float16* w1t_lo = (_Float16*)falloc(4 * 64 * 64 / 2 + 16);
  _Float16* w2t_hi = (_Float16*)falloc(4 * 64 * 64 / 2 + 16);
  _Float16* w2t_lo = (_Float16*)falloc(4 * 64 * 64 / 2 + 16);

  setup_kernel<<<10, 256, 0, stream>>>(W1, a1, W2, bcnt, gcnt, aggXhi, aggXlo,
                                       w1a, w1b, w1t_hi, w1t_lo, w2t_hi, w2t_lo);
  bhist_kernel<<<PA_BLOCKS, 256, 0, stream>>>(dst, bcnt);
  bscan_kernel<<<1, 1024, 0, stream>>>(bcnt, bbase, bcursor, offsets);
  bpart_kernel<<<PA_BLOCKS, 256, 0, stream>>>(src, dst, bcursor, ebuf);
  bcsr_e1_kernel<<<NBUCK + E1_BLK, 256, 0, stream>>>(ebuf, bbase, offsets, srcs,
                                                     gcnt, Ls, Lm,
                                                     user_table, item_table,
                                                     w1a, w1b, e1s, e1d);

  aggX_kernel<<<AGG_MBLK + AGG_SBLK, 256, 0, stream>>>(Ls, Lm, gcnt, offsets, srcs,
                                                       e1s, e1d, user_table,
                                                       item_table, aggXhi, aggXlo);
  trans_mfma_kernel<<<TBLK2, 256, 0, stream>>>(aggXhi, aggXlo,
                                               w1t_hi, w1t_lo, w2t_hi, w2t_lo,
                                               a2, h2, e2s, e2d);

  agg2f_kernel<<<(BATCH + 3) / 4, 256, 0, stream>>>(offsets, srcs, e2s, e2d,
                                                    user_ids, item_ids, h2,
                                                    user_table, item_table, out);
}

// Round 13
// 467.957 us; speedup vs baseline: 1.2132x; 1.0010x over previous
//
#include <hip/hip_runtime.h>
#include <cstdint>
#include <cstddef>

#define NUM_USERS 100000
#define NUM_ITEMS 50000
#define NUM_NODES 150000
#define NUM_EDGES 2000000
#define BATCH 16384
#define BSHIFT 8                                   // 256 nodes per bucket
#define NBUCK ((NUM_NODES + 255) >> BSHIFT)        // 586 buckets
#define PA_EDGES 8192                              // edges per block, bhist/bpart
#define PA_BLOCKS ((NUM_EDGES + PA_EDGES - 1) / PA_EDGES)  // 245
#define NNPAD 150016                               // NUM_NODES rounded to 128
#define TBLK2 (NNPAD / 128)                        // 1172 blocks (4 waves x 32 nodes)
#define AGG_MBLK ((NNPAD + 3) / 4)                 // mid-path blocks (1 node/wave)
#define AGG_SBLK ((NNPAD + 15) / 16)               // small-path blocks (4 nodes/wave)
#define E1_BLK ((NNPAD + 15) / 16)                 // e1 blocks (16 nodes/block)

typedef _Float16 hf8 __attribute__((ext_vector_type(8)));
typedef _Float16 hf4 __attribute__((ext_vector_type(4)));
typedef float fx4 __attribute__((ext_vector_type(4)));

// ---------------- setup: counters zero + aggX pad-row zero + prep (merged) -------------
__global__ void setup_kernel(const float* __restrict__ W1, const float* __restrict__ a1,
                             const float* __restrict__ W2,
                             int* __restrict__ bcnt, int* __restrict__ gcnt,
                             _Float16* __restrict__ aXhi, _Float16* __restrict__ aXlo,
                             float* __restrict__ w1a, float* __restrict__ w1b,
                             _Float16* __restrict__ w1t_hi, _Float16* __restrict__ w1t_lo,
                             _Float16* __restrict__ w2t_hi, _Float16* __restrict__ w2t_lo) {
  int t = threadIdx.x;
  if (blockIdx.x < 8) {
    int i = blockIdx.x * 256 + t;
    if (i < NBUCK) bcnt[i] = 0;
    if (i < 2) gcnt[i] = 0;
    if (i < 2048) {  // 16 pad rows x 256 halves = 2048 floats per plane
      ((float*)(aXhi + (size_t)NUM_NODES * 256))[i] = 0.f;
      ((float*)(aXlo + (size_t)NUM_NODES * 256))[i] = 0.f;
    }
    return;
  }
  int h = t >> 6;
  if (blockIdx.x == 8) {
    int k = t & 63;
    float sa = 0.f, sb = 0.f;
    for (int f = 0; f < 64; ++f) {
      float w = W1[(size_t)k * 256 + h * 64 + f];
      sa += w * a1[h * 128 + f];
      sb += w * a1[h * 128 + 64 + f];
    }
    w1a[h * 64 + k] = sa;
    w1b[h * 64 + k] = sb;
  } else {
    int a = t & 63;
    for (int k = 0; k < 64; ++k) {
      float w = W1[(size_t)k * 256 + h * 64 + a] * 256.f;
      _Float16 hi = (_Float16)w;
      w1t_hi[(size_t)(h * 64 + a) * 64 + k] = hi;
      w1t_lo[(size_t)(h * 64 + a) * 64 + k] = (_Float16)(w - (float)hi);
      float v = W2[(size_t)(h * 64 + k) * 64 + a] * 256.f;
      _Float16 hi2 = (_Float16)v;
      w2t_hi[(size_t)(h * 64 + a) * 64 + k] = hi2;
      w2t_lo[(size_t)(h * 64 + a) * 64 + k] = (_Float16)(v - (float)hi2);
    }
  }
}

// ---------------- bucketed CSR construction ----------------
__global__ __launch_bounds__(256) void bhist_kernel(const int* __restrict__ dst,
                                                    int* __restrict__ bcnt) {
  __shared__ int bh[NBUCK];
  int t = threadIdx.x;
  for (int u = t; u < NBUCK; u += 256) bh[u] = 0;
  __syncthreads();
  int base = blockIdx.x * PA_EDGES;
#pragma unroll
  for (int u = 0; u < PA_EDGES / 256; ++u) {
    int e = base + u * 256 + t;
    if (e < NUM_EDGES) atomicAdd(&bh[dst[e] >> BSHIFT], 1);
  }
  __syncthreads();
  for (int u = t; u < NBUCK; u += 256) {
    int v = bh[u];
    if (v) atomicAdd(&bcnt[u], v);
  }
}

__global__ void bscan_kernel(const int* __restrict__ bcnt, int* __restrict__ bbase,
                             int* __restrict__ bcursor, int* __restrict__ offsets) {
  __shared__ int sh[1024];
  int t = threadIdx.x;
  int v = (t < NBUCK) ? bcnt[t] : 0;
  sh[t] = v;
  __syncthreads();
  for (int off = 1; off < 1024; off <<= 1) {
    int x = (t >= off) ? sh[t - off] : 0;
    __syncthreads();
    sh[t] += x;
    __syncthreads();
  }
  if (t < NBUCK) {
    bbase[t] = sh[t] - v;
    bcursor[t] = sh[t] - v;
  }
  if (t == NBUCK - 1) {
    bbase[NBUCK] = sh[t];
    offsets[NUM_NODES] = sh[t];  // == NUM_EDGES
  }
}

__global__ __launch_bounds__(256) void bpart_kernel(const int* __restrict__ src,
                                                    const int* __restrict__ dst,
                                                    int* __restrict__ bcursor,
                                                    int2* __restrict__ ebuf) {
  __shared__ int lcnt[NBUCK];
  __shared__ int lbase[NBUCK];
  int t = threadIdx.x;
  for (int u = t; u < NBUCK; u += 256) lcnt[u] = 0;
  __syncthreads();
  int base = blockIdx.x * PA_EDGES;
#pragma unroll
  for (int u = 0; u < PA_EDGES / 256; ++u) {
    int e = base + u * 256 + t;
    if (e < NUM_EDGES) atomicAdd(&lcnt[dst[e] >> BSHIFT], 1);
  }
  __syncthreads();
  for (int u = t; u < NBUCK; u += 256) {
    int v = lcnt[u];
    lbase[u] = v ? atomicAdd(&bcursor[u], v) : 0;
    lcnt[u] = 0;
  }
  __syncthreads();
#pragma unroll
  for (int u = 0; u < PA_EDGES / 256; ++u) {
    int e = base + u * 256 + t;
    if (e < NUM_EDGES) {
      int d = dst[e];
      int b = d >> BSHIFT;
      int p = lbase[b] + atomicAdd(&lcnt[b], 1);
      ebuf[p] = make_int2(src[e], d);
    }
  }
}

__device__ __forceinline__ const float* row_ptr(int s, const float* __restrict__ ut,
                                                const float* __restrict__ it) {
  return (s < NUM_USERS) ? ut + (size_t)s * 64 : it + (size_t)(s - NUM_USERS) * 64;
}

// bcsr (+deg classification) with e1g appended as extra blocks (independent workloads)
__global__ __launch_bounds__(256) void bcsr_e1_kernel(
    const int2* __restrict__ ebuf, const int* __restrict__ bbase,
    int* __restrict__ offsets, int* __restrict__ srcs,
    int* __restrict__ gcnt, int* __restrict__ Ls, int* __restrict__ Lm,
    const float* __restrict__ ut, const float* __restrict__ it,
    const float* __restrict__ w1a, const float* __restrict__ w1b,
    float* __restrict__ e1s, float* __restrict__ e1d) {
  __shared__ int ncnt[256];
  __shared__ int sh[256];
  __shared__ int lcur[256];
  __shared__ int c0, c1, b0, b1;
  int t = threadIdx.x;

  if (blockIdx.x >= NBUCK) {
    // ---------- e1 tables: 4 nodes per wave, 16 lanes per node ----------
    int wave = t >> 6, lane = t & 63;
    int g = lane >> 4, fl = lane & 15;
    int node = (blockIdx.x - NBUCK) * 16 + wave * 4 + g;
    bool valid = node < NUM_NODES;
    float4 xv = make_float4(0.f, 0.f, 0.f, 0.f);
    if (valid) xv = *(const float4*)(row_ptr(node, ut, it) + fl * 4);
    float ps[4], pd[4];
#pragma unroll
    for (int h = 0; h < 4; ++h) {
      float4 wa = *(const float4*)(w1a + h * 64 + fl * 4);
      float4 wb = *(const float4*)(w1b + h * 64 + fl * 4);
      ps[h] = xv.x * wa.x + xv.y * wa.y + xv.z * wa.z + xv.w * wa.w;
      pd[h] = xv.x * wb.x + xv.y * wb.y + xv.z * wb.z + xv.w * wb.w;
    }
#pragma unroll
    for (int off = 8; off; off >>= 1) {
#pragma unroll
      for (int h = 0; h < 4; ++h) {
        ps[h] += __shfl_xor(ps[h], off, 16);
        pd[h] += __shfl_xor(pd[h], off, 16);
      }
    }
    if (valid && fl == 0) {
      *(float4*)(e1s + (size_t)node * 4) = make_float4(ps[0], ps[1], ps[2], ps[3]);
      *(float4*)(e1d + (size_t)node * 4) = make_float4(pd[0], pd[1], pd[2], pd[3]);
    }
    return;
  }

  // ---------- bcsr ----------
  int b = blockIdx.x;
  int node0 = b << BSHIFT;
  int ebeg = bbase[b], eend = bbase[b + 1];
  ncnt[t] = 0;
  if (t == 0) { c0 = 0; c1 = 0; }
  __syncthreads();
  for (int i = ebeg + t; i < eend; i += 256)
    atomicAdd(&ncnt[ebuf[i].y - node0], 1);
  __syncthreads();
  int v = ncnt[t];
  sh[t] = v;
  __syncthreads();
  for (int off = 1; off < 256; off <<= 1) {
    int x = (t >= off) ? sh[t - off] : 0;
    __syncthreads();
    sh[t] += x;
    __syncthreads();
  }
  int excl = ebeg + sh[t] - v;
  if (node0 + t < NUM_NODES) offsets[node0 + t] = excl;
  lcur[t] = excl;
  int cls = -1, rank = 0;
  if (node0 + t < NUM_NODES) {
    cls = (v <= 16) ? 0 : 1;
    rank = atomicAdd(cls == 0 ? &c0 : &c1, 1);
  }
  __syncthreads();
  if (t == 0) {
    b0 = atomicAdd(&gcnt[0], c0);
    b1 = atomicAdd(&gcnt[1], c1);
  }
  __syncthreads();
  if (cls == 0) Ls[b0 + rank] = node0 + t;
  else if (cls == 1) Lm[b1 + rank] = node0 + t;
  for (int i = ebeg + t; i < eend; i += 256) {
    int2 ed = ebuf[i];
    int p = atomicAdd(&lcur[ed.y - node0], 1);
    srcs[p] = ed.x;
  }
}

__device__ __forceinline__ float lrexp(float x) {
  x = x > 0.f ? x : 0.2f * x;
  return __expf(x);
}

__device__ __forceinline__ float wnorm(float w) {
  float sum = w;
#pragma unroll
  for (int off = 32; off; off >>= 1) sum += __shfl_xor(sum, off, 64);
  return w * (1.f / (sum + 1e-8f));
}

__device__ __forceinline__ void fold4(float4& a) {
#pragma unroll
  for (int off = 16; off <= 32; off <<= 1) {
    a.x += __shfl_xor(a.x, off, 64);
    a.y += __shfl_xor(a.y, off, 64);
    a.z += __shfl_xor(a.z, off, 64);
    a.w += __shfl_xor(a.w, off, 64);
  }
}

__device__ __forceinline__ float elu(float x) {
  return x > 0.f ? x : (__expf(x) - 1.f);
}

// split x*256 into f16 hi + f16 lo (exact pow2 scale keeps lo out of denormals)
__device__ __forceinline__ void split4(float4 o, hf4& hv, hf4& lv) {
  float a0 = o.x * 256.f, a1 = o.y * 256.f, a2 = o.z * 256.f, a3 = o.w * 256.f;
  _Float16 h0 = (_Float16)a0, h1 = (_Float16)a1;
  _Float16 h2 = (_Float16)a2, h3 = (_Float16)a3;
  hv[0] = h0; hv[1] = h1; hv[2] = h2; hv[3] = h3;
  lv[0] = (_Float16)(a0 - (float)h0);
  lv[1] = (_Float16)(a1 - (float)h1);
  lv[2] = (_Float16)(a2 - (float)h2);
  lv[3] = (_Float16)(a3 - (float)h3);
}

__device__ __forceinline__ void splitstore(_Float16* __restrict__ hi,
                                           _Float16* __restrict__ lo,
                                           size_t idx, float v) {
  v *= 256.f;
  _Float16 h = (_Float16)v;
  hi[idx] = h;
  lo[idx] = (_Float16)(v - (float)h);
}

// ---------------- merged aggregation (verified R11/R12 body, unchanged) ----------------
__global__ __launch_bounds__(256) void aggX_kernel(
    const int* __restrict__ Ls, const int* __restrict__ Lm,
    const int* __restrict__ gcnt,
    const int* __restrict__ offsets, const int* __restrict__ srcs,
    const float* __restrict__ e1s, const float* __restrict__ e1d,
    const float* __restrict__ ut, const float* __restrict__ it,
    _Float16* __restrict__ aXhi, _Float16* __restrict__ aXlo) {
  __shared__ int sS[4][68];                       // [wave][g*17 + e] (small path)
  __shared__ __align__(16) float4 sW[4][68];
  const int t = threadIdx.x;
  const int wave = t >> 6, lane = t & 63;
  const int g = lane >> 4, fl = lane & 15;

  if (blockIdx.x < AGG_MBLK) {
    // ---------- mid/big path (deg>16): 1 node/wave ----------
    int idx = blockIdx.x * 4 + wave;
    if (idx >= gcnt[1]) return;
    int node = Lm[idx];
    int beg = offsets[node], end = offsets[node + 1];
    int deg = end - beg;

    float edv0 = e1d[(size_t)node * 4 + 0];
    float edv1 = e1d[(size_t)node * 4 + 1];
    float edv2 = e1d[(size_t)node * 4 + 2];
    float edv3 = e1d[(size_t)node * 4 + 3];

    if (deg <= 64) {
      int s = 0;
      float w0 = 0.f, w1 = 0.f, w2 = 0.f, w3 = 0.f;
      if (lane < deg) {
        s = srcs[beg + lane];
        float4 ev = *(const float4*)(e1s + (size_t)s * 4);
        w0 = lrexp(ev.x + edv0);
        w1 = lrexp(ev.y + edv1);
        w2 = lrexp(ev.z + edv2);
        w3 = lrexp(ev.w + edv3);
      }
      w0 = wnorm(w0);
      w1 = wnorm(w1);
      w2 = wnorm(w2);
      w3 = wnorm(w3);

      float4 acc0 = make_float4(0.f, 0.f, 0.f, 0.f);
      float4 acc1 = acc0, acc2 = acc0, acc3 = acc0;
      for (int ebase = 0; ebase < deg; ebase += 16) {
        int i0 = ebase + g, i1 = ebase + 4 + g, i2 = ebase + 8 + g, i3 = ebase + 12 + g;
        int s0 = __shfl(s, i0, 64), s1 = __shfl(s, i1, 64);
        int s2 = __shfl(s, i2, 64), s3 = __shfl(s, i3, 64);
        float4 x0 = *(const float4*)(row_ptr(s0, ut, it) + fl * 4);
        float4 x1 = *(const float4*)(row_ptr(s1, ut, it) + fl * 4);
        float4 x2 = *(const float4*)(row_ptr(s2, ut, it) + fl * 4);
        float4 x3 = *(const float4*)(row_ptr(s3, ut, it) + fl * 4);
#pragma unroll
        for (int j = 0; j < 4; ++j) {
          int ei = ebase + j * 4 + g;
          float4 xv = (j == 0) ? x0 : (j == 1) ? x1 : (j == 2) ? x2 : x3;
          float wg0 = __shfl(w0, ei, 64);
          acc0.x += wg0 * xv.x; acc0.y += wg0 * xv.y;
          acc0.z += wg0 * xv.z; acc0.w += wg0 * xv.w;
          float wg1 = __shfl(w1, ei, 64);
          acc1.x += wg1 * xv.x; acc1.y += wg1 * xv.y;
          acc1.z += wg1 * xv.z; acc1.w += wg1 * xv.w;
          float wg2 = __shfl(w2, ei, 64);
          acc2.x += wg2 * xv.x; acc2.y += wg2 * xv.y;
          acc2.z += wg2 * xv.z; acc2.w += wg2 * xv.w;
          float wg3 = __shfl(w3, ei, 64);
          acc3.x += wg3 * xv.x; acc3.y += wg3 * xv.y;
          acc3.z += wg3 * xv.z; acc3.w += wg3 * xv.w;
        }
      }
      fold4(acc0); fold4(acc1); fold4(acc2); fold4(acc3);

      float4 o = (g == 0) ? acc0 : (g == 1) ? acc1 : (g == 2) ? acc2 : acc3;
      hf4 hv, lv;
      split4(o, hv, lv);
      *(hf4*)(aXhi + (size_t)node * 256 + lane * 4) = hv;
      *(hf4*)(aXlo + (size_t)node * 256 + lane * 4) = lv;
    } else {
      // generic fallback (deg > 64): lane = feature
      float s0 = 0.f, s1 = 0.f, s2 = 0.f, s3 = 0.f;
      for (int e = beg + lane; e < end; e += 64) {
        int s = srcs[e];
        float4 ev = *(const float4*)(e1s + (size_t)s * 4);
        s0 += lrexp(ev.x + edv0); s1 += lrexp(ev.y + edv1);
        s2 += lrexp(ev.z + edv2); s3 += lrexp(ev.w + edv3);
      }
#pragma unroll
      for (int off = 32; off; off >>= 1) {
        s0 += __shfl_xor(s0, off, 64);
        s1 += __shfl_xor(s1, off, 64);
        s2 += __shfl_xor(s2, off, 64);
        s3 += __shfl_xor(s3, off, 64);
      }
      float i0 = 1.f / (s0 + 1e-8f), i1 = 1.f / (s1 + 1e-8f);
      float i2 = 1.f / (s2 + 1e-8f), i3 = 1.f / (s3 + 1e-8f);
      float a0 = 0.f, a1 = 0.f, a2 = 0.f, a3 = 0.f;
      for (int e = beg; e < end; ++e) {
        int sn = srcs[e];
        float xv = row_ptr(sn, ut, it)[lane];
        float4 ev = *(const float4*)(e1s + (size_t)sn * 4);
        a0 += lrexp(ev.x + edv0) * i0 * xv;
        a1 += lrexp(ev.y + edv1) * i1 * xv;
        a2 += lrexp(ev.z + edv2) * i2 * xv;
        a3 += lrexp(ev.w + edv3) * i3 * xv;
      }
      splitstore(aXhi, aXlo, (size_t)node * 256 + 0 * 64 + lane, a0);
      splitstore(aXhi, aXlo, (size_t)node * 256 + 1 * 64 + lane, a1);
      splitstore(aXhi, aXlo, (size_t)node * 256 + 2 * 64 + lane, a2);
      splitstore(aXhi, aXlo, (size_t)node * 256 + 3 * 64 + lane, a3);
    }
    return;
  }

  // ---------- small path (deg<=16): 4 nodes/wave, 16 lanes/node ----------
  const int cnt = gcnt[0];
  const int widx = (blockIdx.x - AGG_MBLK) * 16 + wave * 4 + g;
  const int node = (widx < cnt) ? Ls[widx] : -1;

  int beg = 0, deg = 0;
  float4 ed = make_float4(0.f, 0.f, 0.f, 0.f);
  if (node >= 0) {
    beg = offsets[node];
    deg = offsets[node + 1] - beg;
    ed = *(const float4*)(e1d + (size_t)node * 4);   // broadcast within group
  }
  int s = 0;
  float w0 = 0.f, w1 = 0.f, w2 = 0.f, w3 = 0.f;
  if (fl < deg) {
    s = srcs[beg + fl];
    float4 ev = *(const float4*)(e1s + (size_t)s * 4);
    w0 = lrexp(ev.x + ed.x);
    w1 = lrexp(ev.y + ed.y);
    w2 = lrexp(ev.z + ed.z);
    w3 = lrexp(ev.w + ed.w);
  }
  float t0 = w0, t1 = w1, t2 = w2, t3 = w3;
#pragma unroll
  for (int off = 8; off; off >>= 1) {
    t0 += __shfl_xor(t0, off, 16);
    t1 += __shfl_xor(t1, off, 16);
    t2 += __shfl_xor(t2, off, 16);
    t3 += __shfl_xor(t3, off, 16);
  }
  w0 *= 1.f / (t0 + 1e-8f);
  w1 *= 1.f / (t1 + 1e-8f);
  w2 *= 1.f / (t2 + 1e-8f);
  w3 *= 1.f / (t3 + 1e-8f);
  sS[wave][g * 17 + fl] = s;
  sW[wave][g * 17 + fl] = make_float4(w0, w1, w2, w3);
  // no barrier needed: same-wave LDS write->read ordered by lgkmcnt

  float4 xr[16];
#pragma unroll
  for (int e = 0; e < 16; ++e) {
    int se = sS[wave][g * 17 + e];                 // broadcast read
    xr[e] = *(const float4*)(row_ptr(se, ut, it) + fl * 4);
  }

  float4 a0 = make_float4(0.f, 0.f, 0.f, 0.f);
  float4 a1 = a0, a2 = a0, a3 = a0;
#pragma unroll
  for (int e = 0; e < 16; ++e) {
    float4 w4 = sW[wave][g * 17 + e];
    float4 xv = xr[e];
    a0.x += w4.x * xv.x; a0.y += w4.x * xv.y; a0.z += w4.x * xv.z; a0.w += w4.x * xv.w;
    a1.x += w4.y * xv.x; a1.y += w4.y * xv.y; a1.z += w4.y * xv.z; a1.w += w4.y * xv.w;
    a2.x += w4.z * xv.x; a2.y += w4.z * xv.y; a2.z += w4.z * xv.z; a2.w += w4.z * xv.w;
    a3.x += w4.w * xv.x; a3.y += w4.w * xv.y; a3.z += w4.w * xv.z; a3.w += w4.w * xv.w;
  }
  if (node >= 0) {
    hf4 hv, lv;
    split4(a0, hv, lv);
    *(hf4*)(aXhi + (size_t)node * 256 + 0 * 64 + fl * 4) = hv;
    *(hf4*)(aXlo + (size_t)node * 256 + 0 * 64 + fl * 4) = lv;
    split4(a1, hv, lv);
    *(hf4*)(aXhi + (size_t)node * 256 + 1 * 64 + fl * 4) = hv;
    *(hf4*)(aXlo + (size_t)node * 256 + 1 * 64 + fl * 4) = lv;
    split4(a2, hv, lv);
    *(hf4*)(aXhi + (size_t)node * 256 + 2 * 64 + fl * 4) = hv;
    *(hf4*)(aXlo + (size_t)node * 256 + 2 * 64 + fl * 4) = lv;
    split4(a3, hv, lv);
    *(hf4*)(aXhi + (size_t)node * 256 + 3 * 64 + fl * 4) = hv;
    *(hf4*)(aXlo + (size_t)node * 256 + 3 * 64 + fl * 4) = lv;
  }
}

__device__ __forceinline__ fx4 mfma3(fx4 c, hf8 ah, hf8 al, hf8 bh, hf8 bl) {
  c = __builtin_amdgcn_mfma_f32_16x16x32_f16(ah, bh, c, 0, 0, 0);
  c = __builtin_amdgcn_mfma_f32_16x16x32_f16(al, bh, c, 0, 0, 0);
  c = __builtin_amdgcn_mfma_f32_16x16x32_f16(ah, bl, c, 0, 0, 0);
  return c;
}

// ---------------- dense transform on the MATRIX pipe (verified R8 version) ----------
__global__ __launch_bounds__(256, 2) void trans_mfma_kernel(
    const _Float16* __restrict__ aXhi, const _Float16* __restrict__ aXlo,
    const _Float16* __restrict__ w1t_hi, const _Float16* __restrict__ w1t_lo,
    const _Float16* __restrict__ w2t_hi, const _Float16* __restrict__ w2t_lo,
    const float* __restrict__ a2v,
    float* __restrict__ h2g, float* __restrict__ e2s, float* __restrict__ e2d) {
  __shared__ __align__(16) _Float16 t1hi[4][32 * 64];
  __shared__ __align__(16) _Float16 t1lo[4][32 * 64];
  const int wave = threadIdx.x >> 6;
  const int l = threadIdx.x & 63;
  const int lr = l & 15, lg = l >> 4;
  const int node0 = (blockIdx.x * 4 + wave) * 32;
  char* myhi = (char*)&t1hi[wave][0];
  char* mylo = (char*)&t1lo[wave][0];
  const float DS = 1.52587890625e-05f;  // 2^-16

  const size_t xbase0 = (size_t)(node0 + 0 * 16 + lr) * 256 + lg * 8;
  const size_t xbase1 = (size_t)(node0 + 1 * 16 + lr) * 256 + lg * 8;

  fx4 acc2[4][2];
#pragma unroll
  for (int m = 0; m < 4; ++m)
#pragma unroll
    for (int n = 0; n < 2; ++n) acc2[m][n] = (fx4){0.f, 0.f, 0.f, 0.f};

  // X fragments for the current head: [ks*2+n]
  hf8 cxh[4], cxl[4];
#pragma unroll
  for (int ks = 0; ks < 2; ++ks) {
    cxh[ks * 2 + 0] = *(const hf8*)(aXhi + xbase0 + ks * 32);
    cxl[ks * 2 + 0] = *(const hf8*)(aXlo + xbase0 + ks * 32);
    cxh[ks * 2 + 1] = *(const hf8*)(aXhi + xbase1 + ks * 32);
    cxl[ks * 2 + 1] = *(const hf8*)(aXlo + xbase1 + ks * 32);
  }

#pragma unroll
  for (int h = 0; h < 4; ++h) {
    fx4 acc1[4][2];
#pragma unroll
    for (int m = 0; m < 4; ++m)
#pragma unroll
      for (int n = 0; n < 2; ++n) acc1[m][n] = (fx4){0.f, 0.f, 0.f, 0.f};

    // ---- GEMM1: acc1 = W1h^T @ X^T (last use of cx for this head) ----
#pragma unroll
    for (int ks = 0; ks < 2; ++ks) {
      const int ko = ks * 32 + lg * 8;
#pragma unroll
      for (int m = 0; m < 4; ++m) {
        size_t wo = (size_t)((h * 64 + m * 16 + lr) * 64 + ko);
        hf8 wah = *(const hf8*)(w1t_hi + wo);
        hf8 wal = *(const hf8*)(w1t_lo + wo);
#pragma unroll
        for (int n = 0; n < 2; ++n)
          acc1[m][n] = mfma3(acc1[m][n], wah, wal, cxh[ks * 2 + n], cxl[ks * 2 + n]);
      }
    }

    // reload cx for next head now; drains under epilogue + GEMM2
    if (h < 3) {
#pragma unroll
      for (int ks = 0; ks < 2; ++ks) {
        cxh[ks * 2 + 0] = *(const hf8*)(aXhi + xbase0 + (h + 1) * 64 + ks * 32);
        cxl[ks * 2 + 0] = *(const hf8*)(aXlo + xbase0 + (h + 1) * 64 + ks * 32);
        cxh[ks * 2 + 1] = *(const hf8*)(aXhi + xbase1 + (h + 1) * 64 + ks * 32);
        cxl[ks * 2 + 1] = *(const hf8*)(aXlo + xbase1 + (h + 1) * 64 + ks * 32);
      }
    }

    // ---- epilogue: scale, ELU, re-split, write t1 planes to LDS ----
#pragma unroll
    for (int m = 0; m < 4; ++m)
#pragma unroll
      for (int n = 0; n < 2; ++n) {
        hf4 hv, lv;
#pragma unroll
        for (int r = 0; r < 4; ++r) {
          float v = acc1[m][n][r] * DS;
          v = elu(v) * 256.f;
          _Float16 hi = (_Float16)v;
          hv[r] = hi;
          lv[r] = (_Float16)(v - (float)hi);
        }
        int nl = n * 16 + lr;
        int ro = (m * 32 + lg * 8) ^ ((nl & 7) << 4);
        *(hf4*)(myhi + nl * 128 + ro) = hv;
        *(hf4*)(mylo + nl * 128 + ro) = lv;
      }
    // per-wave LDS slice: same-wave DS FIFO orders write->read, no barrier

    // ---- GEMM2: acc2 += W2h^T @ t1^T ----
#pragma unroll
    for (int ks = 0; ks < 2; ++ks) {
      const int ko = ks * 32 + lg * 8;
      hf8 tbh[2], tbl[2];
#pragma unroll
      for (int n = 0; n < 2; ++n) {
        int nl = n * 16 + lr;
        int ro = (ks * 64 + lg * 16) ^ ((nl & 7) << 4);
        tbh[n] = *(const hf8*)(myhi + nl * 128 + ro);
        tbl[n] = *(const hf8*)(mylo + nl * 128 + ro);
      }
#pragma unroll
      for (int m = 0; m < 4; ++m) {
        size_t wo = (size_t)((h * 64 + m * 16 + lr) * 64 + ko);
        hf8 wah = *(const hf8*)(w2t_hi + wo);
        hf8 wal = *(const hf8*)(w2t_lo + wo);
#pragma unroll
        for (int n = 0; n < 2; ++n)
          acc2[m][n] = mfma3(acc2[m][n], wah, wal, tbh[n], tbl[n]);
      }
    }
  }

  // ---- h2 store + e2s/e2d dots ----
  float ps[2] = {0.f, 0.f};
  float pd[2] = {0.f, 0.f};
#pragma unroll
  for (int m = 0; m < 4; ++m) {
    fx4 al = *(const fx4*)(a2v + m * 16 + lg * 4);
    fx4 ar = *(const fx4*)(a2v + 64 + m * 16 + lg * 4);
#pragma unroll
    for (int n = 0; n < 2; ++n) {
      fx4 v = acc2[m][n] * DS;
      int node = node0 + n * 16 + lr;
      if (node < NUM_NODES)
        *(fx4*)(h2g + (size_t)node * 64 + m * 16 + lg * 4) = v;
      ps[n] += v[0] * al[0] + v[1] * al[1] + v[2] * al[2] + v[3] * al[3];
      pd[n] += v[0] * ar[0] + v[1] * ar[1] + v[2] * ar[2] + v[3] * ar[3];
    }
  }
#pragma unroll
  for (int n = 0; n < 2; ++n) {
    float s = ps[n], d = pd[n];
    s += __shfl_xor(s, 16, 64);
    s += __shfl_xor(s, 32, 64);
    d += __shfl_xor(d, 16, 64);
    d += __shfl_xor(d, 32, 64);
    int node = node0 + n * 16 + lr;
    if (lg == n && node < NUM_NODES) {
      e2s[node] = s;
      e2d[node] = d;
    }
  }
}

// ---------------- fused layer-2 aggregation + final dot --------------------
// One wave per NODE (full parallelism restored vs R12's serial u,v); pairs exchange
// rows via LDS and even waves compute the dot. Block = 4 waves = 2 pairs; grid =
// BATCH/2 exactly (BATCH even -> no guards, all waves reach the barrier).
__global__ __launch_bounds__(256) void agg2f_kernel(
    const int* __restrict__ offsets, const int* __restrict__ srcs,
    const float* __restrict__ e2s, const float* __restrict__ e2d,
    const int* __restrict__ uid, const int* __restrict__ iid,
    const float* __restrict__ h2, const float* __restrict__ ut,
    const float* __restrict__ it, float* __restrict__ out) {
  __shared__ __align__(16) float rows[4][64];
  int w = threadIdx.x >> 6, lane = threadIdx.x & 63;
  int pair = blockIdx.x * 2 + (w >> 1);
  int node = ((w & 1) == 0) ? uid[pair] : (NUM_USERS + iid[pair]);
  int beg = offsets[node], end = offsets[node + 1];
  int deg = end - beg;
  float edv = e2d[node];
  const float* rp = row_ptr(node, ut, it);
  const int g = lane >> 4, fl = lane & 15;

  if (deg <= 64) {
    int s = 0;
    float wt = 0.f;
    if (lane < deg) {
      s = srcs[beg + lane];
      wt = lrexp(e2s[s] + edv);
    }
    wt = wnorm(wt);
    float4 acc = make_float4(0.f, 0.f, 0.f, 0.f);
#pragma unroll 4
    for (int e = 0; e < deg; e += 4) {
      int ei = e + g;
      int sg = __shfl(s, ei, 64);
      float wg = __shfl(wt, ei, 64);
      float4 hv = *(const float4*)(h2 + (size_t)sg * 64 + fl * 4);
      acc.x += wg * hv.x; acc.y += wg * hv.y; acc.z += wg * hv.z; acc.w += wg * hv.w;
    }
    fold4(acc);
    if (g == 0) {
      float4 res = *(const float4*)(rp + fl * 4);
      acc.x += res.x; acc.y += res.y; acc.z += res.z; acc.w += res.w;
      *(float4*)&rows[w][fl * 4] = acc;
    }
  } else {
    float psum = 0.f;
    for (int e = beg + lane; e < end; e += 64) {
      int s = srcs[e];
      psum += lrexp(e2s[s] + edv);
    }
#pragma unroll
    for (int off = 32; off; off >>= 1) psum += __shfl_xor(psum, off, 64);
    float inv = 1.f / (psum + 1e-8f);
    float acc = 0.f;
    for (int e = beg; e < end; ++e) {
      int s0 = srcs[e];
      acc += lrexp(e2s[s0] + edv) * inv * h2[(size_t)s0 * 64 + lane];
    }
    acc += rp[lane];
    rows[w][lane] = acc;
  }
  __syncthreads();
  if ((w & 1) == 0) {
    float pr = rows[w][lane] * rows[w + 1][lane];
#pragma unroll
    for (int off = 32; off; off >>= 1) pr += __shfl_xor(pr, off, 64);
    if (lane == 0) out[pair] = pr;
  }
}

extern "C" void kernel_launch(void* const* d_in, const int* in_sizes, int n_in,
                              void* d_out, int out_size, void* d_ws, size_t ws_size,
                              hipStream_t stream) {
  const float* user_table = (const float*)d_in[0];
  const float* item_table = (const float*)d_in[1];
  const float* W1 = (const float*)d_in[2];
  const float* a1 = (const float*)d_in[3];
  const float* W2 = (const float*)d_in[4];
  const float* a2 = (const float*)d_in[5];
  const int* edge_index = (const int*)d_in[6];
  const int* user_ids = (const int*)d_in[7];
  const int* item_ids = (const int*)d_in[8];
  float* out = (float*)d_out;

  const int* src = edge_index;
  const int* dst = edge_index + NUM_EDGES;

  // ---- workspace layout (elements) ----
  float* ws = (float*)d_ws;
  size_t off = 0;
  auto falloc = [&](size_t n) { float* p = ws + off; off += n; return p; };
  float* h2  = falloc((size_t)NUM_NODES * 64);
  float* e1s = falloc((size_t)NUM_NODES * 4);
  float* e1d = falloc((size_t)NUM_NODES * 4);
  float* e2s = falloc(NUM_NODES);
  float* e2d = falloc(NUM_NODES);
  float* w1a = falloc(256);
  float* w1b = falloc(256);
  int* offsets  = (int*)falloc(NUM_NODES + 1);
  int* srcs     = (int*)falloc(NUM_EDGES);
  int* bcnt     = (int*)falloc(NBUCK);
  int* bbase    = (int*)falloc(NBUCK + 1);
  int* bcursor  = (int*)falloc(NBUCK);
  int* gcnt     = (int*)falloc(2);
  int* Ls       = (int*)falloc(NNPAD);
  int* Lm       = (int*)falloc(NNPAD);
  off = (off + 3) & ~(size_t)3;  // 16B-align the f16 planes
  _Float16* aggXhi = (_Float16*)(ws + off); off += (size_t)NNPAD * 128;
  _Float16* aggXlo = (_Float16*)(ws + off); off += (size_t)NNPAD * 128;

  // ebuf (16 MB) aliases plane head — dead before aggX writes (pad rows at +76.8MB safe).
  int2* ebuf = (int2*)aggXhi;
  // weight f16 planes: fresh allocation (128 KB), no lifetime conflicts
  _Float16* w1t_hi = (_Float16*)falloc(4 * 64 * 64 / 2 + 16);
  _Float16* w1t_lo = (_Float16*)falloc(4 * 64 * 64 / 2 + 16);
  _Float16* w2t_hi = (_Float16*)falloc(4 * 64 * 64 / 2 + 16);
  _Float16* w2t_lo = (_Float16*)falloc(4 * 64 * 64 / 2 + 16);

  setup_kernel<<<10, 256, 0, stream>>>(W1, a1, W2, bcnt, gcnt, aggXhi, aggXlo,
                                       w1a, w1b, w1t_hi, w1t_lo, w2t_hi, w2t_lo);
  bhist_kernel<<<PA_BLOCKS, 256, 0, stream>>>(dst, bcnt);
  bscan_kernel<<<1, 1024, 0, stream>>>(bcnt, bbase, bcursor, offsets);
  bpart_kernel<<<PA_BLOCKS, 256, 0, stream>>>(src, dst, bcursor, ebuf);
  bcsr_e1_kernel<<<NBUCK + E1_BLK, 256, 0, stream>>>(ebuf, bbase, offsets, srcs,
                                                     gcnt, Ls, Lm,
                                                     user_table, item_table,
                                                     w1a, w1b, e1s, e1d);

  aggX_kernel<<<AGG_MBLK + AGG_SBLK, 256, 0, stream>>>(Ls, Lm, gcnt, offsets, srcs,
                                                       e1s, e1d, user_table,
                                                       item_table, aggXhi, aggXlo);
  trans_mfma_kernel<<<TBLK2, 256, 0, stream>>>(aggXhi, aggXlo,
                                               w1t_hi, w1t_lo, w2t_hi, w2t_lo,
                                               a2, h2, e2s, e2d);

  agg2f_kernel<<<BATCH / 2, 256, 0, stream>>>(offsets, srcs, e2s, e2d,
                                              user_ids, item_ids, h2,
                                              user_table, item_table, out);
}